// Round 1
// baseline (1833.403 us; speedup 1.0000x reference)
//
#include <hip/hip_runtime.h>
#include <cmath>

#define D 160
#define DD (D*D)
#define NVOX (D*D*D)
#define BIGV (NVOX + 2)
#define NBINS 4096
#define HALF 16

// ---------------------------------------------------------------------------
// 1D box filter ('same', window 32: [i-16, i+15]) along one axis.
// Two running prefix sums reproduce the reference's cumsum-difference exactly
// (same addition order) -> integer box sums (cw) are bit-exact.
// segval >= 0: input is raw data, element = (rint(data)==segval) ? 1 : 0.
// accvalid: instead of writing the sum, accumulate (sum > 100) into out
// (used for the final axis pass of cw0 / cw2 -> valid accumulation).
// ---------------------------------------------------------------------------
__global__ __launch_bounds__(256) void box1d_kernel(
    const float* __restrict__ in, float* __restrict__ out,
    int axis, float segval, int accvalid)
{
    int l = blockIdx.x * blockDim.x + threadIdx.x;
    if (l >= DD) return;
    int a = l / D, b = l - a * D;
    int base, stride;
    if (axis == 0)      { base = a * D + b;       stride = DD; }
    else if (axis == 1) { base = a * DD + b;      stride = D;  }
    else                { base = (a * D + b) * D; stride = 1;  }

    float s_hi = 0.f, s_lo = 0.f;
    #pragma unroll 1
    for (int j = 0; j < 15; ++j) {
        float x = in[base + j * stride];
        if (segval >= 0.f) x = (rintf(x) == segval) ? 1.f : 0.f;
        s_hi += x;
    }
    #pragma unroll 1
    for (int i = 0; i < D; ++i) {
        int hi = i + 15;
        if (hi < D) {
            float x = in[base + hi * stride];
            if (segval >= 0.f) x = (rintf(x) == segval) ? 1.f : 0.f;
            s_hi += x;
        }
        float s = s_hi - s_lo;
        int q = base + i * stride;
        if (accvalid) out[q] += (s > 100.f) ? 1.f : 0.f;
        else          out[q] = s;
        int lo = i - 16;
        if (lo >= 0) {
            float x = in[base + lo * stride];
            if (segval >= 0.f) x = (rintf(x) == segval) ? 1.f : 0.f;
            s_lo += x;
        }
    }
}

// ---------------------------------------------------------------------------
// CCL (6-connectivity min propagation, 16 synchronous sweeps) for seg = (data==1)
// ---------------------------------------------------------------------------
__global__ __launch_bounds__(256) void ccl_init_kernel(
    const float* __restrict__ data, int* __restrict__ lab)
{
    int p = blockIdx.x * blockDim.x + threadIdx.x;
    if (p >= NVOX) return;
    lab[p] = (rintf(data[p]) == 1.f) ? (p + 1) : BIGV;
}

__global__ __launch_bounds__(256) void ccl_sweep_kernel(
    const float* __restrict__ data, const int* __restrict__ lab,
    int* __restrict__ out)
{
    int p = blockIdx.x * blockDim.x + threadIdx.x;
    if (p >= NVOX) return;
    if (rintf(data[p]) != 1.f) { out[p] = BIGV; return; }
    int z = p % D;
    int t = p / D;
    int y = t % D;
    int x = t / D;
    int m = lab[p];
    if (z > 0)     m = min(m, lab[p - 1]);
    if (z < D - 1) m = min(m, lab[p + 1]);
    if (y > 0)     m = min(m, lab[p - D]);
    if (y < D - 1) m = min(m, lab[p + D]);
    if (x > 0)     m = min(m, lab[p - DD]);
    if (x < D - 1) m = min(m, lab[p + DD]);
    out[p] = m;
}

__global__ __launch_bounds__(256) void ccl_count_kernel(
    const float* __restrict__ data, const int* __restrict__ lab,
    int* __restrict__ cnt)
{
    int p = blockIdx.x * blockDim.x + threadIdx.x;
    if (p >= NVOX) return;
    if (rintf(data[p]) == 1.f) atomicAdd(&cnt[lab[p]], 1);
}

// lsize * valid1  -> out (input for the cs box filter)
__global__ __launch_bounds__(256) void lsize_valid_kernel(
    const float* __restrict__ data, const int* __restrict__ lab,
    const int* __restrict__ cnt, const float* __restrict__ cw1,
    float* __restrict__ out)
{
    int p = blockIdx.x * blockDim.x + threadIdx.x;
    if (p >= NVOX) return;
    float ls = (rintf(data[p]) == 1.f) ? (float)cnt[lab[p]] : 0.f;
    float v  = (cw1[p] > 100.f) ? 1.f : 0.f;
    out[p] = ls * v;
}

// ---------------------------------------------------------------------------
// finalize: candidates, mean (written into cw1's buffer), histogram of bins
// ---------------------------------------------------------------------------
__global__ __launch_bounds__(256) void finalize_kernel(
    const float* __restrict__ cw1, const float* __restrict__ cs,
    float* __restrict__ cand /* in: valid0+valid2 acc, out: candidates */,
    float* __restrict__ meanout /* == cw1 buffer, aliasing OK elementwise */,
    int* __restrict__ hist)
{
    __shared__ int lh[NBINS];
    for (int i = threadIdx.x; i < NBINS; i += blockDim.x) lh[i] = 0;
    __syncthreads();

    int p = blockIdx.x * blockDim.x + threadIdx.x;
    if (p < NVOX) {
        float cw = cw1[p];
        float v1 = (cw > 100.f) ? 1.f : 0.f;
        int z = p % D;
        int t = p / D;
        int y = t % D;
        int x = t / D;
        float border = (x >= HALF && x < D - HALF &&
                        y >= HALF && y < D - HALF &&
                        z >= HALF && z < D - HALF) ? 1.f : 0.f;
        float fin = border * v1 + cand[p];
        float c = (fin >= 2.f) ? 1.f : 0.f;
        cand[p] = c;
        float mean = (cw > 0.f) ? cs[p] / fmaxf(cw, 1.f) : 0.f;
        meanout[p] = mean;
        float possible = c * mean;
        int idx = (int)rintf(possible);     // round half-to-even, matches jnp.round
        idx = min(max(idx, 0), NBINS - 1);
        atomicAdd(&lh[idx], 1);
    }
    __syncthreads();
    for (int i = threadIdx.x; i < NBINS; i += blockDim.x)
        if (lh[i]) atomicAdd(&hist[i], lh[i]);
}

// ---------------------------------------------------------------------------
// histogram post-processing: rec -> ph_full, and S = sum_p ph_full[idx_p]
// single block, 256 threads
// ---------------------------------------------------------------------------
__global__ __launch_bounds__(256) void hist_post_kernel(
    const int* __restrict__ hist, float* __restrict__ ph_full,
    float* __restrict__ Sout)
{
    __shared__ float red[256];
    int t = threadIdx.x;

    // numb = sum(hist[1:])
    float loc = 0.f;
    for (int b = t; b < NBINS; b += 256)
        if (b >= 1) loc += (float)hist[b];
    red[t] = loc; __syncthreads();
    for (int o = 128; o > 0; o >>= 1) { if (t < o) red[t] += red[t + o]; __syncthreads(); }
    float numb = red[0]; __syncthreads();

    // rec, sum(rec)
    loc = 0.f;
    for (int b = t; b < NBINS; b += 256) {
        float r = 0.f;
        if (b >= 1) {
            int h = hist[b];
            if (h > 0) r = numb / (float)h;
        }
        ph_full[b] = r;
        loc += r;
    }
    red[t] = loc; __syncthreads();
    for (int o = 128; o > 0; o >>= 1) { if (t < o) red[t] += red[t + o]; __syncthreads(); }
    float sumrec = red[0]; __syncthreads();

    // ph_full normalized; S = sum_b hist[b] * ph_full[b]
    loc = 0.f;
    for (int b = t; b < NBINS; b += 256) {
        float ph = (b >= 1) ? ph_full[b] / sumrec : 0.f;
        ph_full[b] = ph;
        loc += ph * (float)hist[b];
    }
    red[t] = loc; __syncthreads();
    for (int o = 128; o > 0; o >>= 1) { if (t < o) red[t] += red[t + o]; __syncthreads(); }
    if (t == 0) Sout[0] = red[0];
}

// ---------------------------------------------------------------------------
// final proba output: ph_full[idx] / S
// ---------------------------------------------------------------------------
__global__ __launch_bounds__(256) void proba_kernel(
    const float* __restrict__ cand, const float* __restrict__ meanbuf,
    const float* __restrict__ ph_full, const float* __restrict__ Sv,
    float* __restrict__ outp)
{
    int p = blockIdx.x * blockDim.x + threadIdx.x;
    if (p >= NVOX) return;
    float possible = cand[p] * meanbuf[p];
    int idx = (int)rintf(possible);
    idx = min(max(idx, 0), NBINS - 1);
    outp[p] = ph_full[idx] / Sv[0];
}

// ---------------------------------------------------------------------------
extern "C" void kernel_launch(void* const* d_in, const int* in_sizes, int n_in,
                              void* d_out, int out_size, void* d_ws, size_t ws_size,
                              hipStream_t stream)
{
    const float* data = (const float*)d_in[0];
    float* out   = (float*)d_out;
    float* cand  = out;          // first NVOX floats
    float* proba = out + NVOX;   // second NVOX floats

    char* ws = (char*)d_ws;
    const size_t NB = (size_t)NVOX * sizeof(float); // 16,384,000
    float* t1   = (float*)(ws);
    float* t2   = (float*)(ws + NB);
    float* cw1  = (float*)(ws + 2 * NB);
    int*   cnt  = (int*)  (ws + 3 * NB);                    // NVOX+1 ints
    float* ph   = (float*)(ws + 3 * NB + NB + 16);          // 4096 floats
    int*   hist = (int*)  (ws + 3 * NB + NB + 16 + NBINS * 4);
    float* Sv   = (float*)(ws + 3 * NB + NB + 16 + 2 * NBINS * 4);

    int* lab_a = (int*)t1;
    int* lab_b = (int*)t2;

    dim3 eb(256), eg(NVOX / 256);          // 16000 blocks, exact
    dim3 lb(256), lg((DD + 255) / 256);    // 100 blocks

    hipMemsetAsync(cand, 0, NB, stream);
    hipMemsetAsync(cnt, 0, (NVOX + 1) * sizeof(int), stream);
    hipMemsetAsync(hist, 0, NBINS * sizeof(int), stream);

    // cw0: box_sum(data==0) -> accumulate (cw>100) into cand
    box1d_kernel<<<lg, lb, 0, stream>>>(data, t1, 0, 0.f, 0);
    box1d_kernel<<<lg, lb, 0, stream>>>(t1, t2, 1, -1.f, 0);
    box1d_kernel<<<lg, lb, 0, stream>>>(t2, cand, 2, -1.f, 1);
    // cw2
    box1d_kernel<<<lg, lb, 0, stream>>>(data, t1, 0, 2.f, 0);
    box1d_kernel<<<lg, lb, 0, stream>>>(t1, t2, 1, -1.f, 0);
    box1d_kernel<<<lg, lb, 0, stream>>>(t2, cand, 2, -1.f, 1);
    // cw1 (kept raw for mean)
    box1d_kernel<<<lg, lb, 0, stream>>>(data, t1, 0, 1.f, 0);
    box1d_kernel<<<lg, lb, 0, stream>>>(t1, t2, 1, -1.f, 0);
    box1d_kernel<<<lg, lb, 0, stream>>>(t2, cw1, 2, -1.f, 0);

    // CCL for v=1 (t1/t2 are free now; reuse as label ping-pong)
    ccl_init_kernel<<<eg, eb, 0, stream>>>(data, lab_a);
    for (int s = 0; s < 16; ++s) {
        const int* src = (s & 1) ? lab_b : lab_a;
        int*       dst = (s & 1) ? lab_a : lab_b;
        ccl_sweep_kernel<<<eg, eb, 0, stream>>>(data, src, dst);
    }
    // result in lab_a after 16 sweeps
    ccl_count_kernel<<<eg, eb, 0, stream>>>(data, lab_a, cnt);
    lsize_valid_kernel<<<eg, eb, 0, stream>>>(data, lab_a, cnt, cw1, t2);

    // cs = box_sum(lsize*valid1): t2 -> t1 -> t2 -> t1
    box1d_kernel<<<lg, lb, 0, stream>>>(t2, t1, 0, -1.f, 0);
    box1d_kernel<<<lg, lb, 0, stream>>>(t1, t2, 1, -1.f, 0);
    box1d_kernel<<<lg, lb, 0, stream>>>(t2, t1, 2, -1.f, 0);

    // candidates + mean (into cw1 buffer) + histogram
    finalize_kernel<<<eg, eb, 0, stream>>>(cw1, t1, cand, cw1, hist);
    hist_post_kernel<<<1, 256, 0, stream>>>(hist, ph, Sv);
    proba_kernel<<<eg, eb, 0, stream>>>(cand, cw1, ph, Sv, proba);
}

// Round 2
// 1082.243 us; speedup vs baseline: 1.6941x; 1.6941x over previous
//
#include <hip/hip_runtime.h>
#include <cmath>

#define D 160
#define DD (D*D)
#define NVOX (D*D*D)
#define BIGV (NVOX + 2)
#define NBINS 4096
#define HALF 16

// ---------------------------------------------------------------------------
// pack + CCL init: one elementwise pass over data.
// packed = (data==0 ? 1 : 0) | (data==1 ? 1<<16 : 0); lab = seg1 ? p+1 : BIG
// ---------------------------------------------------------------------------
__global__ __launch_bounds__(256) void pack_init_kernel(
    const float* __restrict__ data, unsigned* __restrict__ packed,
    int* __restrict__ lab)
{
    int p = blockIdx.x * blockDim.x + threadIdx.x;
    if (p >= NVOX) return;
    float r = rintf(data[p]);
    unsigned c0 = (r == 0.f) ? 1u : 0u;
    unsigned c1 = (r == 1.f) ? 1u : 0u;
    packed[p] = c0 | (c1 << 16);
    lab[p] = c1 ? (p + 1) : BIGV;
}

// ---------------------------------------------------------------------------
// Packed-int 1D box sum (window 32, 'same'), any order (exact integers).
// 5 segments of 32 per line -> 128000 threads.
// cw0 in low 16 bits, cw1 in high 16 bits (max 32768 each, no carry).
// ---------------------------------------------------------------------------
template<int AXIS>
__global__ __launch_bounds__(256) void boxint_kernel(
    const unsigned* __restrict__ in, unsigned* __restrict__ out)
{
    int t = blockIdx.x * blockDim.x + threadIdx.x;
    if (t >= DD * 5) return;
    int l, s;
    if (AXIS == 2) { l = t / 5; s = t - l * 5; }
    else           { s = t / DD; l = t - s * DD; }
    int base, stride;
    if (AXIS == 0)      { base = l;                         stride = DD; }
    else if (AXIS == 1) { base = (l / D) * DD + (l % D);    stride = D;  }
    else                { base = l * D;                     stride = 1;  }

    int i0 = 32 * s;
    unsigned sum = 0u;
    int jlo = i0 - 16; if (jlo < 0) jlo = 0;
    int jhi = i0 + 15; if (jhi > D - 1) jhi = D - 1;
    for (int j = jlo; j <= jhi; ++j) sum += in[base + j * stride];
    #pragma unroll 4
    for (int k = 0; k < 32; ++k) {
        int i = i0 + k;
        out[base + i * stride] = sum;
        int add = i + 16, rem = i - 16;
        if (add <= D - 1) sum += in[base + add * stride];
        if (rem >= 0)     sum -= in[base + rem * stride];
    }
}

// ---------------------------------------------------------------------------
// Bit-exact float 1D box filter (reference cumsum order): thread-per-line,
// two running sums s_hi == c[i+15], s_lo == c[i-16] (fold-left fp32).
// Used only for the cs = box_sum(lsize*valid) path where rounding matters.
// ---------------------------------------------------------------------------
template<int AXIS>
__global__ __launch_bounds__(256) void boxf_kernel(
    const float* __restrict__ in, float* __restrict__ out)
{
    int l = blockIdx.x * blockDim.x + threadIdx.x;
    if (l >= DD) return;
    int base, stride;
    if (AXIS == 0)      { base = l;                      stride = DD; }
    else if (AXIS == 1) { base = (l / D) * DD + (l % D); stride = D;  }
    else                { base = l * D;                  stride = 1;  }

    float s_hi = 0.f, s_lo = 0.f;
    for (int j = 0; j < 15; ++j) s_hi += in[base + j * stride];
    for (int i = 0; i < D; ++i) {
        int hi = i + 15;
        if (hi < D) s_hi += in[base + hi * stride];
        out[base + i * stride] = s_hi - s_lo;
        int lo = i - 16;
        if (lo >= 0) s_lo += in[base + lo * stride];
    }
}

// ---------------------------------------------------------------------------
// CCL sweep (6-neighbor synchronous min propagation), lab-only.
// Background invariant: lab == BIGV iff voxel not in seg (label of a seg
// voxel never exceeds its own 1-based index).
// ---------------------------------------------------------------------------
__global__ __launch_bounds__(256) void ccl_sweep_kernel(
    const int* __restrict__ lab, int* __restrict__ out)
{
    int p = blockIdx.x * blockDim.x + threadIdx.x;
    if (p >= NVOX) return;
    int m = lab[p];
    if (m == BIGV) { out[p] = BIGV; return; }
    int z = p % D;
    int t = p / D;
    int y = t % D;
    int x = t / D;
    if (z > 0)     m = min(m, lab[p - 1]);
    if (z < D - 1) m = min(m, lab[p + 1]);
    if (y > 0)     m = min(m, lab[p - D]);
    if (y < D - 1) m = min(m, lab[p + D]);
    if (x > 0)     m = min(m, lab[p - DD]);
    if (x < D - 1) m = min(m, lab[p + DD]);
    out[p] = m;
}

__global__ __launch_bounds__(256) void ccl_count_kernel(
    const int* __restrict__ lab, int* __restrict__ cnt)
{
    int p = blockIdx.x * blockDim.x + threadIdx.x;
    if (p >= NVOX) return;
    int l = lab[p];
    if (l != BIGV) atomicAdd(&cnt[l], 1);
}

// lsize * valid1 -> out (float input for the cs box filter)
__global__ __launch_bounds__(256) void lsize_valid_kernel(
    const int* __restrict__ lab, const int* __restrict__ cnt,
    const unsigned* __restrict__ cwp, float* __restrict__ out)
{
    int p = blockIdx.x * blockDim.x + threadIdx.x;
    if (p >= NVOX) return;
    int l = lab[p];
    float ls = 0.f;
    if (l != BIGV) ls = (float)cnt[l];
    unsigned cw1 = cwp[p] >> 16;
    out[p] = (cw1 > 100u) ? ls : 0.f;
}

// ---------------------------------------------------------------------------
// finalize: candidates (out), mean (meanbuf), histogram (skip unused bin 0)
// cw2 derived: total - cw0 - cw1, total = separable clamped window product.
// ---------------------------------------------------------------------------
__global__ __launch_bounds__(256) void finalize_kernel(
    const unsigned* __restrict__ cwp, const float* __restrict__ cs,
    float* __restrict__ cand, float* __restrict__ meanbuf,
    int* __restrict__ hist)
{
    __shared__ int lh[NBINS];
    for (int i = threadIdx.x; i < NBINS; i += blockDim.x) lh[i] = 0;
    __syncthreads();

    int p = blockIdx.x * blockDim.x + threadIdx.x;
    if (p < NVOX) {
        unsigned pk = cwp[p];
        unsigned cw0 = pk & 0xFFFFu;
        unsigned cw1 = pk >> 16;
        int z = p % D;
        int t = p / D;
        int y = t % D;
        int x = t / D;
        int wx = min(x + 15, D - 1) - max(x - 16, 0) + 1;
        int wy = min(y + 15, D - 1) - max(y - 16, 0) + 1;
        int wz = min(z + 15, D - 1) - max(z - 16, 0) + 1;
        unsigned total = (unsigned)(wx * wy * wz);
        unsigned cw2 = total - cw0 - cw1;
        float v0 = (cw0 > 100u) ? 1.f : 0.f;
        float v1 = (cw1 > 100u) ? 1.f : 0.f;
        float v2 = (cw2 > 100u) ? 1.f : 0.f;
        float border = (x >= HALF && x < D - HALF &&
                        y >= HALF && y < D - HALF &&
                        z >= HALF && z < D - HALF) ? 1.f : 0.f;
        float fin = border * v1 + v0 + v2;
        float c = (fin >= 2.f) ? 1.f : 0.f;
        cand[p] = c;
        float mean = (cw1 > 0u) ? cs[p] / fmaxf((float)cw1, 1.f) : 0.f;
        meanbuf[p] = mean;
        int idx = (int)rintf(c * mean);   // round half-to-even == jnp.round
        idx = min(max(idx, 0), NBINS - 1);
        if (idx != 0) atomicAdd(&lh[idx], 1);   // hist[0] is never consumed
    }
    __syncthreads();
    for (int i = threadIdx.x; i < NBINS; i += blockDim.x)
        if (lh[i]) atomicAdd(&hist[i], lh[i]);
}

// ---------------------------------------------------------------------------
// histogram post-processing: rec -> ph_full (normalized), S = sum hist*ph
// ---------------------------------------------------------------------------
__global__ __launch_bounds__(256) void hist_post_kernel(
    const int* __restrict__ hist, float* __restrict__ ph_full,
    float* __restrict__ Sout)
{
    __shared__ float red[256];
    int t = threadIdx.x;

    float loc = 0.f;
    for (int b = t; b < NBINS; b += 256)
        if (b >= 1) loc += (float)hist[b];
    red[t] = loc; __syncthreads();
    for (int o = 128; o > 0; o >>= 1) { if (t < o) red[t] += red[t + o]; __syncthreads(); }
    float numb = red[0]; __syncthreads();

    loc = 0.f;
    for (int b = t; b < NBINS; b += 256) {
        float r = 0.f;
        if (b >= 1) {
            int h = hist[b];
            if (h > 0) r = numb / (float)h;
        }
        ph_full[b] = r;
        loc += r;
    }
    red[t] = loc; __syncthreads();
    for (int o = 128; o > 0; o >>= 1) { if (t < o) red[t] += red[t + o]; __syncthreads(); }
    float sumrec = red[0]; __syncthreads();

    loc = 0.f;
    for (int b = t; b < NBINS; b += 256) {
        float ph = (b >= 1) ? ph_full[b] / sumrec : 0.f;
        ph_full[b] = ph;
        loc += ph * (float)hist[b];
    }
    red[t] = loc; __syncthreads();
    for (int o = 128; o > 0; o >>= 1) { if (t < o) red[t] += red[t + o]; __syncthreads(); }
    if (t == 0) Sout[0] = red[0];
}

__global__ __launch_bounds__(256) void proba_kernel(
    const float* __restrict__ cand, const float* __restrict__ meanbuf,
    const float* __restrict__ ph_full, const float* __restrict__ Sv,
    float* __restrict__ outp)
{
    int p = blockIdx.x * blockDim.x + threadIdx.x;
    if (p >= NVOX) return;
    float possible = cand[p] * meanbuf[p];
    int idx = (int)rintf(possible);
    idx = min(max(idx, 0), NBINS - 1);
    outp[p] = ph_full[idx] / Sv[0];
}

// ---------------------------------------------------------------------------
extern "C" void kernel_launch(void* const* d_in, const int* in_sizes, int n_in,
                              void* d_out, int out_size, void* d_ws, size_t ws_size,
                              hipStream_t stream)
{
    const float* data = (const float*)d_in[0];
    float* out   = (float*)d_out;
    float* cand  = out;          // first NVOX floats
    float* proba = out + NVOX;   // second NVOX floats

    char* ws = (char*)d_ws;
    const size_t NB = (size_t)NVOX * sizeof(float);
    float* W1 = (float*)(ws);
    float* W2 = (float*)(ws + NB);
    float* W3 = (float*)(ws + 2 * NB);
    int*   cnt  = (int*)(ws + 3 * NB);                       // NVOX+1 ints
    float* ph   = (float*)(ws + 4 * NB + 16);                // 4096 floats
    int*   hist = (int*)  (ws + 4 * NB + 16 + NBINS * 4);
    float* Sv   = (float*)(ws + 4 * NB + 16 + 2 * NBINS * 4);

    dim3 eb(256), eg(NVOX / 256);          // 16000 blocks
    dim3 bb(256), bg((DD * 5 + 255) / 256);// 500 blocks (packed box)
    dim3 lb(256), lg((DD + 255) / 256);    // 100 blocks (bit-exact box)

    hipMemsetAsync(cnt, 0, (NVOX + 1) * sizeof(int), stream);
    hipMemsetAsync(hist, 0, NBINS * sizeof(int), stream);

    // 1. pack classes + CCL init:  packed->W1, lab->W2
    pack_init_kernel<<<eg, eb, 0, stream>>>(data, (unsigned*)W1, (int*)W2);

    // 2. packed cw box sums (exact ints, order-free): W1->W3->W1->W3
    boxint_kernel<0><<<bg, bb, 0, stream>>>((unsigned*)W1, (unsigned*)W3);
    boxint_kernel<1><<<bg, bb, 0, stream>>>((unsigned*)W3, (unsigned*)W1);
    boxint_kernel<2><<<bg, bb, 0, stream>>>((unsigned*)W1, (unsigned*)W3);
    unsigned* cwp = (unsigned*)W3;

    // 3. CCL: 16 synchronous sweeps, ping-pong W2 <-> W1
    for (int s = 0; s < 16; ++s) {
        const int* src = (s & 1) ? (int*)W1 : (int*)W2;
        int*       dst = (s & 1) ? (int*)W2 : (int*)W1;
        ccl_sweep_kernel<<<eg, eb, 0, stream>>>(src, dst);
    }
    int* lab = (int*)W2;   // 16 sweeps -> result back in W2

    ccl_count_kernel<<<eg, eb, 0, stream>>>(lab, cnt);
    lsize_valid_kernel<<<eg, eb, 0, stream>>>(lab, cnt, cwp, W1);

    // 4. cs = box_sum(lsize*valid1), bit-exact order axes 0,1,2: W1->W2->W1->W2
    boxf_kernel<0><<<lg, lb, 0, stream>>>(W1, W2);
    boxf_kernel<1><<<lg, lb, 0, stream>>>(W2, W1);
    boxf_kernel<2><<<lg, lb, 0, stream>>>(W1, W2);
    float* cs = W2;

    // 5. candidates + mean + histogram, then proba
    finalize_kernel<<<eg, eb, 0, stream>>>(cwp, cs, cand, W1, hist);
    hist_post_kernel<<<1, 256, 0, stream>>>(hist, ph, Sv);
    proba_kernel<<<eg, eb, 0, stream>>>(cand, W1, ph, Sv, proba);
}

// Round 3
// 955.145 us; speedup vs baseline: 1.9195x; 1.1331x over previous
//
#include <hip/hip_runtime.h>
#include <cmath>

#define D 160
#define DD (D*D)
#define NVOX (D*D*D)
#define BIGV (NVOX + 2)
#define NBINS 4096
#define HALF 16

// ---------------------------------------------------------------------------
// pack + CCL init, 4 voxels/thread.
// packed = (data==0 ? 1 : 0) | (data==1 ? 1<<16 : 0); lab = seg1 ? p+1 : BIG
// ---------------------------------------------------------------------------
__global__ __launch_bounds__(256) void pack_init_kernel(
    const float4* __restrict__ data, uint4* __restrict__ packed,
    int4* __restrict__ lab)
{
    int t = blockIdx.x * blockDim.x + threadIdx.x;   // t < NVOX/4 (exact grid)
    int p = t * 4;
    float4 d = data[t];
    uint4 pk; int4 lb;
    float r;
    r = rintf(d.x); pk.x = (r==0.f) | ((r==1.f)?(1u<<16):0u); lb.x = (r==1.f)?(p+1):BIGV;
    r = rintf(d.y); pk.y = (r==0.f) | ((r==1.f)?(1u<<16):0u); lb.y = (r==1.f)?(p+2):BIGV;
    r = rintf(d.z); pk.z = (r==0.f) | ((r==1.f)?(1u<<16):0u); lb.z = (r==1.f)?(p+3):BIGV;
    r = rintf(d.w); pk.w = (r==0.f) | ((r==1.f)?(1u<<16):0u); lb.w = (r==1.f)?(p+4):BIGV;
    packed[t] = pk; lab[t] = lb;
}

// ---------------------------------------------------------------------------
// Packed-int 1D box sum (window 32, 'same'), order-free (exact integers).
// 5 segments of 32 per line. cw0 low 16 bits, cw1 high 16 bits.
// ---------------------------------------------------------------------------
template<int AXIS>
__global__ __launch_bounds__(256) void boxint_kernel(
    const unsigned* __restrict__ in, unsigned* __restrict__ out)
{
    int t = blockIdx.x * blockDim.x + threadIdx.x;
    if (t >= DD * 5) return;
    int l, s;
    if (AXIS == 2) { l = t / 5; s = t - l * 5; }
    else           { s = t / DD; l = t - s * DD; }
    int base, stride;
    if (AXIS == 0)      { base = l;                         stride = DD; }
    else if (AXIS == 1) { base = (l / D) * DD + (l % D);    stride = D;  }
    else                { base = l * D;                     stride = 1;  }

    int i0 = 32 * s;
    unsigned sum = 0u;
    int jlo = i0 - 16; if (jlo < 0) jlo = 0;
    int jhi = i0 + 15; if (jhi > D - 1) jhi = D - 1;
    for (int j = jlo; j <= jhi; ++j) sum += in[base + j * stride];
    #pragma unroll 4
    for (int k = 0; k < 32; ++k) {
        int i = i0 + k;
        out[base + i * stride] = sum;
        int add = i + 16, rem = i - 16;
        if (add <= D - 1) sum += in[base + add * stride];
        if (rem >= 0)     sum -= in[base + rem * stride];
    }
}

// ---------------------------------------------------------------------------
// Bit-exact float box filter, axes 0/1 (coalesced strided access):
// thread-per-line, running sums s_hi==c[i+15], s_lo==c[i-16], fold-left fp32.
// ---------------------------------------------------------------------------
template<int AXIS>
__global__ __launch_bounds__(256) void boxf_kernel(
    const float* __restrict__ in, float* __restrict__ out)
{
    int l = blockIdx.x * blockDim.x + threadIdx.x;
    if (l >= DD) return;
    int base, stride;
    if (AXIS == 0) { base = l;                      stride = DD; }
    else           { base = (l / D) * DD + (l % D); stride = D;  }

    float s_hi = 0.f, s_lo = 0.f;
    for (int j = 0; j < 15; ++j) s_hi += in[base + j * stride];
    for (int i = 0; i < D; ++i) {
        int hi = i + 15;
        if (hi < D) s_hi += in[base + hi * stride];
        out[base + i * stride] = s_hi - s_lo;
        int lo = i - 16;
        if (lo >= 0) s_lo += in[base + lo * stride];
    }
}

// ---------------------------------------------------------------------------
// Bit-exact float box filter, axis 2 (contiguous rows): LDS-staged.
// Block = 64 threads, 64 contiguous rows (= one contiguous 40 KB chunk).
// Coalesced float4 global loads; per-row fold from LDS (pad 161 -> the
// fold-phase access t[row][j] hits bank (row+j)%32: conflict-free across a
// wave for fixed j). Same fp add sequence as reference cumsum -> bit-exact.
// ---------------------------------------------------------------------------
__global__ __launch_bounds__(64) void boxf2_lds_kernel(
    const float* __restrict__ in, float* __restrict__ out)
{
    __shared__ float t[64][161];
    int row0 = blockIdx.x * 64;
    const float4* s4 = (const float4*)(in + (size_t)row0 * D);
    for (int i = threadIdx.x; i < 64 * (D / 4); i += 64) {
        float4 v = s4[i];
        int e = i * 4, r = e / D, c = e - r * D;
        t[r][c] = v.x; t[r][c+1] = v.y; t[r][c+2] = v.z; t[r][c+3] = v.w;
    }
    __syncthreads();

    int row = threadIdx.x;
    const float* ln = t[row];
    float* gout = out + (size_t)(row0 + row) * D;
    float s_hi = 0.f, s_lo = 0.f;
    for (int j = 0; j < 15; ++j) s_hi += ln[j];
    float ob[4];
    for (int i = 0; i < D; i += 4) {
        #pragma unroll
        for (int k = 0; k < 4; ++k) {
            int i2 = i + k, hi = i2 + 15;
            if (hi < D) s_hi += ln[hi];
            ob[k] = s_hi - s_lo;
            int lo = i2 - 16;
            if (lo >= 0) s_lo += ln[lo];
        }
        *(float4*)(gout + i) = make_float4(ob[0], ob[1], ob[2], ob[3]);
    }
}

// ---------------------------------------------------------------------------
// CCL sweep, 4 voxels/thread (int4). Background invariant: lab==BIGV iff
// not in seg. All-background quads early-out.
// ---------------------------------------------------------------------------
__global__ __launch_bounds__(256) void ccl_sweep4_kernel(
    const int4* __restrict__ lab4, const int* __restrict__ lab,
    int4* __restrict__ out)
{
    int t = blockIdx.x * blockDim.x + threadIdx.x;   // t < NVOX/4 (exact grid)
    int p = t * 4;
    int4 c = lab4[t];
    if (c.x == BIGV && c.y == BIGV && c.z == BIGV && c.w == BIGV) {
        out[t] = c; return;
    }
    int z = p % D;
    int r = p / D;
    int y = r % D;
    int x = r / D;
    const int4 BIG4 = make_int4(BIGV, BIGV, BIGV, BIGV);
    int lm = (z > 0)     ? lab[p - 1] : BIGV;
    int rm = (z < D - 4) ? lab[p + 4] : BIGV;
    int4 yl = (y > 0)     ? lab4[t - D/4]  : BIG4;
    int4 yh = (y < D - 1) ? lab4[t + D/4]  : BIG4;
    int4 xl = (x > 0)     ? lab4[t - DD/4] : BIG4;
    int4 xh = (x < D - 1) ? lab4[t + DD/4] : BIG4;
    int4 o;
    o.x = (c.x == BIGV) ? BIGV : min(min(min(c.x, lm),  c.y), min(min(yl.x, yh.x), min(xl.x, xh.x)));
    o.y = (c.y == BIGV) ? BIGV : min(min(min(c.y, c.x), c.z), min(min(yl.y, yh.y), min(xl.y, xh.y)));
    o.z = (c.z == BIGV) ? BIGV : min(min(min(c.z, c.y), c.w), min(min(yl.z, yh.z), min(xl.z, xh.z)));
    o.w = (c.w == BIGV) ? BIGV : min(min(min(c.w, c.z), rm),  min(min(yl.w, yh.w), min(xl.w, xh.w)));
    out[t] = o;
}

// ---------------------------------------------------------------------------
// Component-size count with wave-level dedup: labels are constant over long
// runs -> ~few distinct labels per wave -> one atomic per distinct label.
// ---------------------------------------------------------------------------
__global__ __launch_bounds__(256) void ccl_count_kernel(
    const int* __restrict__ lab, int* __restrict__ cnt)
{
    int p = blockIdx.x * blockDim.x + threadIdx.x;   // exact grid
    int l = lab[p];
    int lane = threadIdx.x & 63;
    unsigned long long remaining = __ballot(l != BIGV);
    while (remaining) {
        int leader = __ffsll(remaining) - 1;
        int ll = __shfl(l, leader, 64);
        unsigned long long mm = __ballot(l == ll);
        if (lane == leader) atomicAdd(&cnt[ll], (int)__popcll(mm & remaining));
        remaining &= ~mm;
    }
}

// lsize * valid1 -> out (float input for the cs box filter), 4 voxels/thread
__global__ __launch_bounds__(256) void lsize_valid_kernel(
    const int4* __restrict__ lab4, const int* __restrict__ cnt,
    const uint4* __restrict__ cwp4, float4* __restrict__ out)
{
    int t = blockIdx.x * blockDim.x + threadIdx.x;   // exact grid
    int4 l = lab4[t];
    uint4 cw = cwp4[t];
    float4 o;
    o.x = (l.x != BIGV && (cw.x >> 16) > 100u) ? (float)cnt[l.x] : 0.f;
    o.y = (l.y != BIGV && (cw.y >> 16) > 100u) ? (float)cnt[l.y] : 0.f;
    o.z = (l.z != BIGV && (cw.z >> 16) > 100u) ? (float)cnt[l.z] : 0.f;
    o.w = (l.w != BIGV && (cw.w >> 16) > 100u) ? (float)cnt[l.w] : 0.f;
    out[t] = o;
}

// ---------------------------------------------------------------------------
// finalize: candidates (out), idx (ushort), histogram with wave-dedup
// aggregation (smooth mean -> ~1-3 distinct bins per wave -> ~1-3 LDS
// atomics per wave instead of 64 serialized same-bank hits).
// ---------------------------------------------------------------------------
__global__ __launch_bounds__(256) void finalize_kernel(
    const unsigned* __restrict__ cwp, const float* __restrict__ cs,
    float* __restrict__ cand, unsigned short* __restrict__ idxbuf,
    int* __restrict__ hist)
{
    __shared__ int lh[NBINS];
    for (int i = threadIdx.x; i < NBINS; i += blockDim.x) lh[i] = 0;
    __syncthreads();

    int p = blockIdx.x * blockDim.x + threadIdx.x;   // exact grid (=NVOX)
    unsigned pk = cwp[p];
    unsigned cw0 = pk & 0xFFFFu;
    unsigned cw1 = pk >> 16;
    int z = p % D;
    int r = p / D;
    int y = r % D;
    int x = r / D;
    int wx = min(x + 15, D - 1) - max(x - 16, 0) + 1;
    int wy = min(y + 15, D - 1) - max(y - 16, 0) + 1;
    int wz = min(z + 15, D - 1) - max(z - 16, 0) + 1;
    unsigned cw2 = (unsigned)(wx * wy * wz) - cw0 - cw1;
    float v0 = (cw0 > 100u) ? 1.f : 0.f;
    float v1 = (cw1 > 100u) ? 1.f : 0.f;
    float v2 = (cw2 > 100u) ? 1.f : 0.f;
    float border = (x >= HALF && x < D - HALF &&
                    y >= HALF && y < D - HALF &&
                    z >= HALF && z < D - HALF) ? 1.f : 0.f;
    float c = (border * v1 + v0 + v2 >= 2.f) ? 1.f : 0.f;
    cand[p] = c;
    float mean = (cw1 > 0u) ? cs[p] / fmaxf((float)cw1, 1.f) : 0.f;
    int idx = (int)rintf(c * mean);      // round half-to-even == jnp.round
    idx = min(max(idx, 0), NBINS - 1);
    idxbuf[p] = (unsigned short)idx;

    int lane = threadIdx.x & 63;
    unsigned long long remaining = __ballot(idx != 0);  // hist[0] never consumed
    while (remaining) {
        int leader = __ffsll(remaining) - 1;
        int li = __shfl(idx, leader, 64);
        unsigned long long mm = __ballot(idx == li);
        if (lane == leader) atomicAdd(&lh[li], (int)__popcll(mm & remaining));
        remaining &= ~mm;
    }
    __syncthreads();
    for (int i = threadIdx.x; i < NBINS; i += blockDim.x)
        if (lh[i]) atomicAdd(&hist[i], lh[i]);
}

// ---------------------------------------------------------------------------
// histogram post-processing: rec -> ph_full (normalized), S = sum hist*ph
// ---------------------------------------------------------------------------
__global__ __launch_bounds__(256) void hist_post_kernel(
    const int* __restrict__ hist, float* __restrict__ ph_full,
    float* __restrict__ Sout)
{
    __shared__ float red[256];
    int t = threadIdx.x;

    float loc = 0.f;
    for (int b = t; b < NBINS; b += 256)
        if (b >= 1) loc += (float)hist[b];
    red[t] = loc; __syncthreads();
    for (int o = 128; o > 0; o >>= 1) { if (t < o) red[t] += red[t + o]; __syncthreads(); }
    float numb = red[0]; __syncthreads();

    loc = 0.f;
    for (int b = t; b < NBINS; b += 256) {
        float r = 0.f;
        if (b >= 1) {
            int h = hist[b];
            if (h > 0) r = numb / (float)h;
        }
        ph_full[b] = r;
        loc += r;
    }
    red[t] = loc; __syncthreads();
    for (int o = 128; o > 0; o >>= 1) { if (t < o) red[t] += red[t + o]; __syncthreads(); }
    float sumrec = red[0]; __syncthreads();

    loc = 0.f;
    for (int b = t; b < NBINS; b += 256) {
        float ph = (b >= 1) ? ph_full[b] / sumrec : 0.f;
        ph_full[b] = ph;
        loc += ph * (float)hist[b];
    }
    red[t] = loc; __syncthreads();
    for (int o = 128; o > 0; o >>= 1) { if (t < o) red[t] += red[t + o]; __syncthreads(); }
    if (t == 0) Sout[0] = red[0];
}

__global__ __launch_bounds__(256) void proba_kernel(
    const unsigned short* __restrict__ idxbuf,
    const float* __restrict__ ph_full, const float* __restrict__ Sv,
    float* __restrict__ outp)
{
    int p = blockIdx.x * blockDim.x + threadIdx.x;   // exact grid
    outp[p] = ph_full[idxbuf[p]] / Sv[0];
}

// ---------------------------------------------------------------------------
extern "C" void kernel_launch(void* const* d_in, const int* in_sizes, int n_in,
                              void* d_out, int out_size, void* d_ws, size_t ws_size,
                              hipStream_t stream)
{
    const float* data = (const float*)d_in[0];
    float* out   = (float*)d_out;
    float* cand  = out;
    float* proba = out + NVOX;

    char* ws = (char*)d_ws;
    const size_t NB = (size_t)NVOX * sizeof(float);
    float* W1 = (float*)(ws);
    float* W2 = (float*)(ws + NB);
    float* W3 = (float*)(ws + 2 * NB);
    int*   cnt  = (int*)(ws + 3 * NB);                 // NVOX+1 ints; reused as idxbuf after last read
    float* ph   = (float*)(ws + 4 * NB + 16);
    int*   hist = (int*)  (ws + 4 * NB + 16 + NBINS * 4);
    float* Sv   = (float*)(ws + 4 * NB + 16 + 2 * NBINS * 4);
    unsigned short* idxbuf = (unsigned short*)cnt;     // cnt dead after lsize_valid

    dim3 eb(256), eg(NVOX / 256);          // 16000 blocks (scalar elementwise)
    dim3 qb(256), qg(NVOX / 4 / 256);      // 4000 blocks  (quad elementwise)
    dim3 bb(256), bg((DD * 5 + 255) / 256);// 500 blocks   (packed box)
    dim3 lb(256), lg((DD + 255) / 256);    // 100 blocks   (boxf axes 0/1)
    dim3 zb(64),  zg(DD / 64);             // 400 blocks   (boxf axis 2, LDS)

    hipMemsetAsync(cnt, 0, (NVOX + 1) * sizeof(int), stream);
    hipMemsetAsync(hist, 0, NBINS * sizeof(int), stream);

    // 1. pack classes + CCL init: packed->W1, lab->W2
    pack_init_kernel<<<qg, qb, 0, stream>>>((const float4*)data, (uint4*)W1, (int4*)W2);

    // 2. packed cw box sums (order-free exact ints): W1->W3->W1->W3
    boxint_kernel<0><<<bg, bb, 0, stream>>>((unsigned*)W1, (unsigned*)W3);
    boxint_kernel<1><<<bg, bb, 0, stream>>>((unsigned*)W3, (unsigned*)W1);
    boxint_kernel<2><<<bg, bb, 0, stream>>>((unsigned*)W1, (unsigned*)W3);
    unsigned* cwp = (unsigned*)W3;

    // 3. CCL: 16 synchronous sweeps, ping-pong W2 <-> W1
    for (int s = 0; s < 16; ++s) {
        const int* src = (s & 1) ? (int*)W1 : (int*)W2;
        int*       dst = (s & 1) ? (int*)W2 : (int*)W1;
        ccl_sweep4_kernel<<<qg, qb, 0, stream>>>((const int4*)src, src, (int4*)dst);
    }
    int* lab = (int*)W2;   // after 16 sweeps result is back in W2

    ccl_count_kernel<<<eg, eb, 0, stream>>>(lab, cnt);
    lsize_valid_kernel<<<qg, qb, 0, stream>>>((const int4*)lab, cnt,
                                              (const uint4*)cwp, (float4*)W1);

    // 4. cs = box_sum(lsize*valid1), bit-exact, axes 0,1,2: W1->W2->W1->W2
    boxf_kernel<0><<<lg, lb, 0, stream>>>(W1, W2);
    boxf_kernel<1><<<lg, lb, 0, stream>>>(W2, W1);
    boxf2_lds_kernel<<<zg, zb, 0, stream>>>(W1, W2);
    float* cs = W2;

    // 5. candidates + idx + histogram, then proba
    finalize_kernel<<<eg, eb, 0, stream>>>(cwp, cs, cand, idxbuf, hist);
    hist_post_kernel<<<1, 256, 0, stream>>>(hist, ph, Sv);
    proba_kernel<<<eg, eb, 0, stream>>>(idxbuf, ph, Sv, proba);
}

// Round 4
// 764.989 us; speedup vs baseline: 2.3966x; 1.2486x over previous
//
#include <hip/hip_runtime.h>
#include <cmath>

#define D 160
#define DD (D*D)
#define NVOX (D*D*D)
#define BIGV (NVOX + 2)
#define NBINS 4096
#define HALF 16
#define S1_BLOCKS 500
#define S1_ITERS 32

// ---------------------------------------------------------------------------
// pack + CCL init, 4 voxels/thread.
// packed = (data==0 ? 1 : 0) | (data==1 ? 1<<16 : 0); lab = seg1 ? p+1 : BIG
// ---------------------------------------------------------------------------
__global__ __launch_bounds__(256) void pack_init_kernel(
    const float4* __restrict__ data, uint4* __restrict__ packed,
    int4* __restrict__ lab)
{
    int t = blockIdx.x * blockDim.x + threadIdx.x;   // exact grid NVOX/4
    int p = t * 4;
    float4 d = data[t];
    uint4 pk; int4 lb;
    float r;
    r = rintf(d.x); pk.x = (r==0.f) | ((r==1.f)?(1u<<16):0u); lb.x = (r==1.f)?(p+1):BIGV;
    r = rintf(d.y); pk.y = (r==0.f) | ((r==1.f)?(1u<<16):0u); lb.y = (r==1.f)?(p+2):BIGV;
    r = rintf(d.z); pk.z = (r==0.f) | ((r==1.f)?(1u<<16):0u); lb.z = (r==1.f)?(p+3):BIGV;
    r = rintf(d.w); pk.w = (r==0.f) | ((r==1.f)?(1u<<16):0u); lb.w = (r==1.f)?(p+4):BIGV;
    packed[t] = pk; lab[t] = lb;
}

// ---------------------------------------------------------------------------
// Packed-int 1D box sum (window 32, 'same'), order-free (exact integers).
// 5 segments of 32 per line. cw0 low 16 bits, cw1 high 16 bits.
// ---------------------------------------------------------------------------
template<int AXIS>
__global__ __launch_bounds__(256) void boxint_kernel(
    const unsigned* __restrict__ in, unsigned* __restrict__ out)
{
    int t = blockIdx.x * blockDim.x + threadIdx.x;
    if (t >= DD * 5) return;
    int l, s;
    if (AXIS == 2) { l = t / 5; s = t - l * 5; }
    else           { s = t / DD; l = t - s * DD; }
    int base, stride;
    if (AXIS == 0)      { base = l;                         stride = DD; }
    else if (AXIS == 1) { base = (l / D) * DD + (l % D);    stride = D;  }
    else                { base = l * D;                     stride = 1;  }

    int i0 = 32 * s;
    unsigned sum = 0u;
    int jlo = i0 - 16; if (jlo < 0) jlo = 0;
    int jhi = i0 + 15; if (jhi > D - 1) jhi = D - 1;
    for (int j = jlo; j <= jhi; ++j) sum += in[base + j * stride];
    #pragma unroll 4
    for (int k = 0; k < 32; ++k) {
        int i = i0 + k;
        out[base + i * stride] = sum;
        int add = i + 16, rem = i - 16;
        if (add <= D - 1) sum += in[base + add * stride];
        if (rem >= 0)     sum -= in[base + rem * stride];
    }
}

// ---------------------------------------------------------------------------
// Bit-exact float box filter, axes 0/1, 5 segments/line (2000 waves).
// Each segment thread recomputes its exact fold-left prefix (identical fp
// add sequence to the reference cumsum), then emits 32 outputs.
// ---------------------------------------------------------------------------
template<int AXIS>
__global__ __launch_bounds__(256) void boxf_seg_kernel(
    const float* __restrict__ in, float* __restrict__ out)
{
    int t = blockIdx.x * blockDim.x + threadIdx.x;   // exact grid DD*5
    int s = t / DD, l = t - s * DD;
    int base, stride;
    if (AXIS == 0) { base = l;                      stride = DD; }
    else           { base = (l / D) * DD + (l % D); stride = D;  }

    int i0 = 32 * s;
    float f = 0.f;
    int jlo = i0 - 16;                 // s_lo = c[i0-17] = fold in[0..i0-17]
    for (int j = 0; j < jlo; ++j) f += in[base + j * stride];
    float s_lo = f;
    for (int j = (jlo > 0 ? jlo : 0); j < i0 + 15; ++j) f += in[base + j * stride];
    float s_hi = f;                    // = c[i0+14]

    #pragma unroll 4
    for (int k = 0; k < 32; ++k) {
        int i = i0 + k, hi = i + 15;
        if (hi < D) s_hi += in[base + hi * stride];
        out[base + i * stride] = s_hi - s_lo;
        int lo = i - 16;
        if (lo >= 0) s_lo += in[base + lo * stride];
    }
}

// ---------------------------------------------------------------------------
// Bit-exact float box filter, axis 2 (contiguous rows): LDS-staged,
// 256 threads = 64 rows x 4 exact segments of 40 outputs.
// Prefix-phase LDS reads: bank (row+j)%32, 2-way aliasing (free, m136).
// ---------------------------------------------------------------------------
__global__ __launch_bounds__(256) void boxf2_lds_kernel(
    const float* __restrict__ in, float* __restrict__ out)
{
    __shared__ float tbl[64][161];
    int row0 = blockIdx.x * 64;
    const float4* s4 = (const float4*)(in + (size_t)row0 * D);
    for (int i = threadIdx.x; i < 64 * (D / 4); i += 256) {
        float4 v = s4[i];
        int e = i * 4, r = e / D, c = e - r * D;
        tbl[r][c] = v.x; tbl[r][c+1] = v.y; tbl[r][c+2] = v.z; tbl[r][c+3] = v.w;
    }
    __syncthreads();

    int row = threadIdx.x & 63;
    int s   = threadIdx.x >> 6;        // 0..3
    const float* ln = tbl[row];
    int i0 = 40 * s;

    float f = 0.f;
    int jlo = i0 - 16;
    for (int j = 0; j < jlo; ++j) f += ln[j];
    float s_lo = f;
    for (int j = (jlo > 0 ? jlo : 0); j < i0 + 15; ++j) f += ln[j];
    float s_hi = f;

    float* gout = out + (size_t)(row0 + row) * D;
    for (int k = 0; k < 40; k += 4) {
        float ob[4];
        #pragma unroll
        for (int kk = 0; kk < 4; ++kk) {
            int i = i0 + k + kk, hi = i + 15;
            if (hi < D) s_hi += ln[hi];
            ob[kk] = s_hi - s_lo;
            int lo = i - 16;
            if (lo >= 0) s_lo += ln[lo];
        }
        *(float4*)(gout + i0 + k) = make_float4(ob[0], ob[1], ob[2], ob[3]);
    }
}

// ---------------------------------------------------------------------------
// CCL sweep, 4 voxels/thread (int4); z-neighbors via wave shuffle of the
// already-loaded center quads (placed BEFORE the early-out so exited lanes
// cannot poison the shuffle). Lane-0/63 and line starts fall back.
// ---------------------------------------------------------------------------
__global__ __launch_bounds__(256) void ccl_sweep4_kernel(
    const int4* __restrict__ lab4, const int* __restrict__ lab,
    int4* __restrict__ out)
{
    int t = blockIdx.x * blockDim.x + threadIdx.x;   // exact grid NVOX/4
    int p = t * 4;
    int4 c = lab4[t];
    int z = p % D;
    int lane = threadIdx.x & 63;

    int lm = __shfl_up(c.w, 1);        // lab[p-1] when same line & lane>0
    int rm = __shfl_down(c.x, 1);      // lab[p+4] when same line & lane<63
    if (z == 0)            lm = BIGV;
    else if (lane == 0)    lm = lab[p - 1];
    if (z >= D - 4)        rm = BIGV;  // last quad of the line
    else if (lane == 63)   rm = lab[p + 4];

    if (c.x == BIGV && c.y == BIGV && c.z == BIGV && c.w == BIGV) {
        out[t] = c; return;
    }
    int r = p / D;
    int y = r % D;
    int x = r / D;
    const int4 BIG4 = make_int4(BIGV, BIGV, BIGV, BIGV);
    int4 yl = (y > 0)     ? lab4[t - D/4]  : BIG4;
    int4 yh = (y < D - 1) ? lab4[t + D/4]  : BIG4;
    int4 xl = (x > 0)     ? lab4[t - DD/4] : BIG4;
    int4 xh = (x < D - 1) ? lab4[t + DD/4] : BIG4;
    int4 o;
    o.x = (c.x == BIGV) ? BIGV : min(min(min(c.x, lm),  c.y), min(min(yl.x, yh.x), min(xl.x, xh.x)));
    o.y = (c.y == BIGV) ? BIGV : min(min(min(c.y, c.x), c.z), min(min(yl.y, yh.y), min(xl.y, xh.y)));
    o.z = (c.z == BIGV) ? BIGV : min(min(min(c.z, c.y), c.w), min(min(yl.z, yh.z), min(xl.z, xh.z)));
    o.w = (c.w == BIGV) ? BIGV : min(min(min(c.w, c.z), rm),  min(min(yl.w, yh.w), min(xl.w, xh.w)));
    out[t] = o;
}

// ---------------------------------------------------------------------------
// Component-size count with wave-level dedup (labels run-length constant).
// ---------------------------------------------------------------------------
__global__ __launch_bounds__(256) void ccl_count_kernel(
    const int* __restrict__ lab, int* __restrict__ cnt)
{
    int p = blockIdx.x * blockDim.x + threadIdx.x;   // exact grid
    int l = lab[p];
    int lane = threadIdx.x & 63;
    unsigned long long remaining = __ballot(l != BIGV);
    while (remaining) {
        int leader = __ffsll(remaining) - 1;
        int ll = __shfl(l, leader, 64);
        unsigned long long mm = __ballot(l == ll);
        if (lane == leader) atomicAdd(&cnt[ll], (int)__popcll(mm & remaining));
        remaining &= ~mm;
    }
}

// lsize * valid1 -> out (float input for the cs box filter), 4 voxels/thread
__global__ __launch_bounds__(256) void lsize_valid_kernel(
    const int4* __restrict__ lab4, const int* __restrict__ cnt,
    const uint4* __restrict__ cwp4, float4* __restrict__ out)
{
    int t = blockIdx.x * blockDim.x + threadIdx.x;   // exact grid
    int4 l = lab4[t];
    uint4 cw = cwp4[t];
    float4 o;
    o.x = (l.x != BIGV && (cw.x >> 16) > 100u) ? (float)cnt[l.x] : 0.f;
    o.y = (l.y != BIGV && (cw.y >> 16) > 100u) ? (float)cnt[l.y] : 0.f;
    o.z = (l.z != BIGV && (cw.z >> 16) > 100u) ? (float)cnt[l.z] : 0.f;
    o.w = (l.w != BIGV && (cw.w >> 16) > 100u) ? (float)cnt[l.w] : 0.f;
    out[t] = o;
}

// ---------------------------------------------------------------------------
// finalize stage 1: candidates (out), idx (ushort), per-block private hist
// flushed with PLAIN coalesced stores (no global atomics -> no XCD same-line
// atomic ping-pong, which was the 186 us bottleneck in R2/R3).
// 500 blocks x 32 grid-stride iterations. LDS atomic scatter measured ~free.
// ---------------------------------------------------------------------------
__global__ __launch_bounds__(256) void finalize_kernel(
    const unsigned* __restrict__ cwp, const float* __restrict__ cs,
    float* __restrict__ cand, unsigned short* __restrict__ idxbuf,
    int* __restrict__ partial)
{
    __shared__ int lh[NBINS];
    for (int i = threadIdx.x; i < NBINS; i += 256) lh[i] = 0;
    __syncthreads();

    int base = blockIdx.x * (256 * S1_ITERS);
    for (int it = 0; it < S1_ITERS; ++it) {
        int p = base + it * 256 + threadIdx.x;
        unsigned pk = cwp[p];
        unsigned cw0 = pk & 0xFFFFu;
        unsigned cw1 = pk >> 16;
        int z = p % D;
        int r = p / D;
        int y = r % D;
        int x = r / D;
        int wx = min(x + 15, D - 1) - max(x - 16, 0) + 1;
        int wy = min(y + 15, D - 1) - max(y - 16, 0) + 1;
        int wz = min(z + 15, D - 1) - max(z - 16, 0) + 1;
        unsigned cw2 = (unsigned)(wx * wy * wz) - cw0 - cw1;
        float v0 = (cw0 > 100u) ? 1.f : 0.f;
        float v1 = (cw1 > 100u) ? 1.f : 0.f;
        float v2 = (cw2 > 100u) ? 1.f : 0.f;
        float border = (x >= HALF && x < D - HALF &&
                        y >= HALF && y < D - HALF &&
                        z >= HALF && z < D - HALF) ? 1.f : 0.f;
        float c = (border * v1 + v0 + v2 >= 2.f) ? 1.f : 0.f;
        cand[p] = c;
        float mean = (cw1 > 0u) ? cs[p] / fmaxf((float)cw1, 1.f) : 0.f;
        int idx = (int)rintf(c * mean);      // round half-to-even == jnp.round
        idx = min(max(idx, 0), NBINS - 1);
        idxbuf[p] = (unsigned short)idx;
        if (idx != 0) atomicAdd(&lh[idx], 1);  // hist[0] never consumed
    }
    __syncthreads();
    int* po = partial + blockIdx.x * NBINS;
    for (int i = threadIdx.x; i < NBINS; i += 256) po[i] = lh[i];
}

// stage 2: hist[bin] = sum over 500 block partials (coalesced, L2-resident)
__global__ __launch_bounds__(256) void hist_reduce_kernel(
    const int* __restrict__ partial, int* __restrict__ hist)
{
    int bin = blockIdx.x * 256 + threadIdx.x;   // 16 blocks x 256 = 4096
    int s = 0;
    #pragma unroll 4
    for (int b = 0; b < S1_BLOCKS; ++b) s += partial[b * NBINS + bin];
    hist[bin] = s;
}

// ---------------------------------------------------------------------------
// histogram post-processing: rec -> ph_full (normalized), S = sum hist*ph
// ---------------------------------------------------------------------------
__global__ __launch_bounds__(256) void hist_post_kernel(
    const int* __restrict__ hist, float* __restrict__ ph_full,
    float* __restrict__ Sout)
{
    __shared__ float red[256];
    int t = threadIdx.x;

    float loc = 0.f;
    for (int b = t; b < NBINS; b += 256)
        if (b >= 1) loc += (float)hist[b];
    red[t] = loc; __syncthreads();
    for (int o = 128; o > 0; o >>= 1) { if (t < o) red[t] += red[t + o]; __syncthreads(); }
    float numb = red[0]; __syncthreads();

    loc = 0.f;
    for (int b = t; b < NBINS; b += 256) {
        float r = 0.f;
        if (b >= 1) {
            int h = hist[b];
            if (h > 0) r = numb / (float)h;
        }
        ph_full[b] = r;
        loc += r;
    }
    red[t] = loc; __syncthreads();
    for (int o = 128; o > 0; o >>= 1) { if (t < o) red[t] += red[t + o]; __syncthreads(); }
    float sumrec = red[0]; __syncthreads();

    loc = 0.f;
    for (int b = t; b < NBINS; b += 256) {
        float ph = (b >= 1) ? ph_full[b] / sumrec : 0.f;
        ph_full[b] = ph;
        loc += ph * (float)hist[b];
    }
    red[t] = loc; __syncthreads();
    for (int o = 128; o > 0; o >>= 1) { if (t < o) red[t] += red[t + o]; __syncthreads(); }
    if (t == 0) Sout[0] = red[0];
}

__global__ __launch_bounds__(256) void proba_kernel(
    const unsigned short* __restrict__ idxbuf,
    const float* __restrict__ ph_full, const float* __restrict__ Sv,
    float* __restrict__ outp)
{
    int p = blockIdx.x * blockDim.x + threadIdx.x;   // exact grid
    outp[p] = ph_full[idxbuf[p]] / Sv[0];
}

// ---------------------------------------------------------------------------
extern "C" void kernel_launch(void* const* d_in, const int* in_sizes, int n_in,
                              void* d_out, int out_size, void* d_ws, size_t ws_size,
                              hipStream_t stream)
{
    const float* data = (const float*)d_in[0];
    float* out   = (float*)d_out;
    float* cand  = out;
    float* proba = out + NVOX;

    char* ws = (char*)d_ws;
    const size_t NB = (size_t)NVOX * sizeof(float);
    float* W1 = (float*)(ws);
    float* W2 = (float*)(ws + NB);
    float* W3 = (float*)(ws + 2 * NB);
    int*   cnt  = (int*)(ws + 3 * NB);                 // NVOX+1 ints
    float* ph   = (float*)(ws + 4 * NB + 16);
    int*   hist = (int*)  (ws + 4 * NB + 16 + NBINS * 4);
    float* Sv   = (float*)(ws + 4 * NB + 16 + 2 * NBINS * 4);
    unsigned short* idxbuf = (unsigned short*)cnt;     // cnt dead after lsize_valid
    int* partial = (int*)W1;                           // W1 dead after boxf chain

    dim3 eb(256), eg(NVOX / 256);          // 16000 blocks (scalar elementwise)
    dim3 qb(256), qg(NVOX / 4 / 256);      // 4000 blocks  (quad elementwise)
    dim3 bb(256), bg((DD * 5 + 255) / 256);// 500 blocks   (segmented box)
    dim3 zb(256), zg(DD / 64);             // 400 blocks   (boxf axis 2, LDS)

    hipMemsetAsync(cnt, 0, (NVOX + 1) * sizeof(int), stream);

    // 1. pack classes + CCL init: packed->W1, lab->W2
    pack_init_kernel<<<qg, qb, 0, stream>>>((const float4*)data, (uint4*)W1, (int4*)W2);

    // 2. packed cw box sums (order-free exact ints): W1->W3->W1->W3
    boxint_kernel<0><<<bg, bb, 0, stream>>>((unsigned*)W1, (unsigned*)W3);
    boxint_kernel<1><<<bg, bb, 0, stream>>>((unsigned*)W3, (unsigned*)W1);
    boxint_kernel<2><<<bg, bb, 0, stream>>>((unsigned*)W1, (unsigned*)W3);
    unsigned* cwp = (unsigned*)W3;

    // 3. CCL: 16 synchronous sweeps, ping-pong W2 <-> W1
    for (int s = 0; s < 16; ++s) {
        const int* src = (s & 1) ? (int*)W1 : (int*)W2;
        int*       dst = (s & 1) ? (int*)W2 : (int*)W1;
        ccl_sweep4_kernel<<<qg, qb, 0, stream>>>((const int4*)src, src, (int4*)dst);
    }
    int* lab = (int*)W2;   // after 16 sweeps result is back in W2

    ccl_count_kernel<<<eg, eb, 0, stream>>>(lab, cnt);
    lsize_valid_kernel<<<qg, qb, 0, stream>>>((const int4*)lab, cnt,
                                              (const uint4*)cwp, (float4*)W1);

    // 4. cs = box_sum(lsize*valid1), bit-exact, axes 0,1,2: W1->W2->W1->W2
    boxf_seg_kernel<0><<<bg, bb, 0, stream>>>(W1, W2);
    boxf_seg_kernel<1><<<bg, bb, 0, stream>>>(W2, W1);
    boxf2_lds_kernel<<<zg, zb, 0, stream>>>(W1, W2);
    float* cs = W2;

    // 5. candidates + idx + two-stage histogram, then proba
    finalize_kernel<<<dim3(S1_BLOCKS), dim3(256), 0, stream>>>(cwp, cs, cand, idxbuf, partial);
    hist_reduce_kernel<<<dim3(16), dim3(256), 0, stream>>>(partial, hist);
    hist_post_kernel<<<1, 256, 0, stream>>>(hist, ph, Sv);
    proba_kernel<<<eg, eb, 0, stream>>>(idxbuf, ph, Sv, proba);
}

// Round 5
// 596.009 us; speedup vs baseline: 3.0761x; 1.2835x over previous
//
#include <hip/hip_runtime.h>
#include <cmath>

#define D 160
#define DD (D*D)          // 25600 = also the number of lines per rotate pass
#define NVOX (D*D*D)
#define BIGV (NVOX + 2)
#define NBINS 4096
#define HALF 16
#define S1_BLOCKS 500
#define S1_ITERS 32

// fused CCL sweep tile
#define FZ 32
#define FY 8
#define FX 8
#define HL 2
#define TZ (FZ + 2*HL)    // 36
#define TY (FY + 2*HL)    // 12
#define TX (FX + 2*HL)    // 12
#define TVOL (TZ*TY*TX)   // 5184

// ---------------------------------------------------------------------------
// Rotate-pipeline box filter (window 32, 'same'), INT packed path.
// Input viewed as [25600 lines][160 elems] (contiguous along filter axis).
// Output written rotated: out[c*25600 + L]. Three applications = identity
// layout with each axis filtered once. All global IO is full-line coalesced.
// MODE 0: input = raw float data -> packs (d==0)|((d==1)<<16), also writes
//         lab (original layout). MODE 1: input = packed u32.
// cw0 low 16 bits, cw1 high 16 bits (max 32768: no carry). Integer box sums
// are exact in any order -> candidates stay bit-exact.
// ---------------------------------------------------------------------------
template<int MODE>
__global__ __launch_bounds__(256) void box_rot_int_kernel(
    const void* __restrict__ vin, unsigned* __restrict__ out,
    int* __restrict__ lab)
{
    __shared__ unsigned tin[32][161];
    __shared__ unsigned filt[160][33];
    int L0 = blockIdx.x * 32;
    size_t base = (size_t)L0 * D;

    if (MODE == 0) {
        const float4* s4 = (const float4*)((const float*)vin + base);
        int4* lab4 = (int4*)(lab + base);
        for (int i = threadIdx.x; i < 32 * (D / 4); i += 256) {
            float4 v = s4[i];
            int e = i * 4, r = e / D, c = e - r * D;
            int p = (int)base + e;
            int4 lb; float rr;
            rr = rintf(v.x); tin[r][c]   = (rr==0.f) | ((rr==1.f)?0x10000u:0u); lb.x = (rr==1.f)?(p+1):BIGV;
            rr = rintf(v.y); tin[r][c+1] = (rr==0.f) | ((rr==1.f)?0x10000u:0u); lb.y = (rr==1.f)?(p+2):BIGV;
            rr = rintf(v.z); tin[r][c+2] = (rr==0.f) | ((rr==1.f)?0x10000u:0u); lb.z = (rr==1.f)?(p+3):BIGV;
            rr = rintf(v.w); tin[r][c+3] = (rr==0.f) | ((rr==1.f)?0x10000u:0u); lb.w = (rr==1.f)?(p+4):BIGV;
            lab4[i] = lb;
        }
    } else {
        const uint4* s4 = (const uint4*)((const unsigned*)vin + base);
        for (int i = threadIdx.x; i < 32 * (D / 4); i += 256) {
            uint4 v = s4[i];
            int e = i * 4, r = e / D, c = e - r * D;
            tin[r][c] = v.x; tin[r][c+1] = v.y; tin[r][c+2] = v.z; tin[r][c+3] = v.w;
        }
    }
    __syncthreads();

    // filter: 32 rows x 8 segments of 20 outputs
    {
        int r = threadIdx.x & 31, s = threadIdx.x >> 5;
        int i0 = 20 * s;
        const unsigned* ln = tin[r];
        unsigned sum = 0u;
        int jlo = i0 - 16; if (jlo < 0) jlo = 0;
        int jhi = i0 + 15; if (jhi > D - 1) jhi = D - 1;
        for (int j = jlo; j <= jhi; ++j) sum += ln[j];
        #pragma unroll 4
        for (int k = 0; k < 20; ++k) {
            int i = i0 + k;
            filt[i][r] = sum;
            int add = i + 16, rem = i - 16;
            if (add <= D - 1) sum += ln[add];
            if (rem >= 0)     sum -= ln[rem];
        }
    }
    __syncthreads();

    // rotated write: half-wave of 32 lanes covers one full 128B line
    int r = threadIdx.x & 31;
    for (int c = (threadIdx.x >> 5); c < D; c += 8)
        out[(size_t)c * DD + L0 + r] = filt[c][r];
}

// ---------------------------------------------------------------------------
// Rotate-pipeline box filter, FLOAT path (cs = box_sum(lsize*valid1)).
// fp summation order differs from the reference cumsum — only perturbs the
// proba path (~1e-7 magnitude vs 2e-2 threshold); candidates are int-exact.
// MODE 0: input = lab + cnt + cwp -> element = (lab!=BIG && cw1>100)?cnt:0.
// MODE 1: plain float input.
// ---------------------------------------------------------------------------
template<int MODE>
__global__ __launch_bounds__(256) void box_rot_f32_kernel(
    const float* __restrict__ fin, const int* __restrict__ lab,
    const int* __restrict__ cnt, const unsigned* __restrict__ cwp,
    float* __restrict__ out)
{
    __shared__ float tin[32][161];
    __shared__ float filt[160][33];
    int L0 = blockIdx.x * 32;
    size_t base = (size_t)L0 * D;

    if (MODE == 0) {
        const int4*  lab4 = (const int4*)(lab + base);
        const uint4* cw4  = (const uint4*)(cwp + base);
        for (int i = threadIdx.x; i < 32 * (D / 4); i += 256) {
            int4 l = lab4[i];
            uint4 cw = cw4[i];
            int e = i * 4, r = e / D, c = e - r * D;
            tin[r][c]   = (l.x != BIGV && (cw.x >> 16) > 100u) ? (float)cnt[l.x] : 0.f;
            tin[r][c+1] = (l.y != BIGV && (cw.y >> 16) > 100u) ? (float)cnt[l.y] : 0.f;
            tin[r][c+2] = (l.z != BIGV && (cw.z >> 16) > 100u) ? (float)cnt[l.z] : 0.f;
            tin[r][c+3] = (l.w != BIGV && (cw.w >> 16) > 100u) ? (float)cnt[l.w] : 0.f;
        }
    } else {
        const float4* s4 = (const float4*)(fin + base);
        for (int i = threadIdx.x; i < 32 * (D / 4); i += 256) {
            float4 v = s4[i];
            int e = i * 4, r = e / D, c = e - r * D;
            tin[r][c] = v.x; tin[r][c+1] = v.y; tin[r][c+2] = v.z; tin[r][c+3] = v.w;
        }
    }
    __syncthreads();

    {
        int r = threadIdx.x & 31, s = threadIdx.x >> 5;
        int i0 = 20 * s;
        const float* ln = tin[r];
        float sum = 0.f;
        int jlo = i0 - 16; if (jlo < 0) jlo = 0;
        int jhi = i0 + 15; if (jhi > D - 1) jhi = D - 1;
        for (int j = jlo; j <= jhi; ++j) sum += ln[j];
        #pragma unroll 4
        for (int k = 0; k < 20; ++k) {
            int i = i0 + k;
            filt[i][r] = sum;
            int add = i + 16, rem = i - 16;
            if (add <= D - 1) sum += ln[add];
            if (rem >= 0)     sum -= ln[rem];
        }
    }
    __syncthreads();

    int r = threadIdx.x & 31;
    for (int c = (threadIdx.x >> 5); c < D; c += 8)
        out[(size_t)c * DD + L0 + r] = filt[c][r];
}

// ---------------------------------------------------------------------------
// Fused 2x CCL sweep: LDS halo-2 tile, two synchronous Jacobi min-sweeps
// with shrinking valid region. Background (BIGV) stays BIGV; out-of-volume
// neighbors = BIGV — identical semantics to two reference sweeps.
// ---------------------------------------------------------------------------
__global__ __launch_bounds__(256) void ccl_sweep2_kernel(
    const int* __restrict__ lab, int* __restrict__ out)
{
    __shared__ int A[TVOL], B[TVOL];
    int b = blockIdx.x;
    int bz = b % 5, t2 = b / 5, by = t2 % 20, bx = t2 / 20;
    int gz0 = bz * FZ - HL, gy0 = by * FY - HL, gx0 = bx * FX - HL;

    for (int i = threadIdx.x; i < TVOL; i += 256) {
        int lz = i % TZ, t = i / TZ, ly = t % TY, lx = t / TY;
        int gz = gz0 + lz, gy = gy0 + ly, gx = gx0 + lx;
        int v = BIGV;
        if ((unsigned)gz < (unsigned)D && (unsigned)gy < (unsigned)D &&
            (unsigned)gx < (unsigned)D)
            v = lab[gx * DD + gy * D + gz];
        A[i] = v;
    }
    __syncthreads();

    // inner sweep 1: halo-1 region (34 x 10 x 10)
    for (int i = threadIdx.x; i < 34 * 10 * 10; i += 256) {
        int lz = i % 34 + 1, t = i / 34, ly = t % 10 + 1, lx = t / 10 + 1;
        int idx = (lx * TY + ly) * TZ + lz;
        int c = A[idx];
        int m = c;
        if (c != BIGV) {
            m = min(m, A[idx - 1]);       m = min(m, A[idx + 1]);
            m = min(m, A[idx - TZ]);      m = min(m, A[idx + TZ]);
            m = min(m, A[idx - TY*TZ]);   m = min(m, A[idx + TY*TZ]);
        }
        B[idx] = m;
    }
    __syncthreads();

    // inner sweep 2: interior (32 x 8 x 8), write out (coalesced 128B lines)
    for (int i = threadIdx.x; i < FZ * FY * FX; i += 256) {
        int lz = i % FZ + HL, t = i / FZ, ly = t % FY + HL, lx = t / FY + HL;
        int idx = (lx * TY + ly) * TZ + lz;
        int c = B[idx];
        int m = c;
        if (c != BIGV) {
            m = min(m, B[idx - 1]);       m = min(m, B[idx + 1]);
            m = min(m, B[idx - TZ]);      m = min(m, B[idx + TZ]);
            m = min(m, B[idx - TY*TZ]);   m = min(m, B[idx + TY*TZ]);
        }
        int gz = gz0 + lz, gy = gy0 + ly, gx = gx0 + lx;
        out[gx * DD + gy * D + gz] = m;
    }
}

// ---------------------------------------------------------------------------
// Component-size count with wave-level dedup (labels run-length constant).
// ---------------------------------------------------------------------------
__global__ __launch_bounds__(256) void ccl_count_kernel(
    const int* __restrict__ lab, int* __restrict__ cnt)
{
    int p = blockIdx.x * blockDim.x + threadIdx.x;   // exact grid
    int l = lab[p];
    int lane = threadIdx.x & 63;
    unsigned long long remaining = __ballot(l != BIGV);
    while (remaining) {
        int leader = __ffsll(remaining) - 1;
        int ll = __shfl(l, leader, 64);
        unsigned long long mm = __ballot(l == ll);
        if (lane == leader) atomicAdd(&cnt[ll], (int)__popcll(mm & remaining));
        remaining &= ~mm;
    }
}

// ---------------------------------------------------------------------------
// finalize stage 1: candidates, idx (ushort), per-block private histogram
// flushed with plain coalesced stores (no global atomics).
// ---------------------------------------------------------------------------
__global__ __launch_bounds__(256) void finalize_kernel(
    const unsigned* __restrict__ cwp, const float* __restrict__ cs,
    float* __restrict__ cand, unsigned short* __restrict__ idxbuf,
    int* __restrict__ partial)
{
    __shared__ int lh[NBINS];
    for (int i = threadIdx.x; i < NBINS; i += 256) lh[i] = 0;
    __syncthreads();

    int base = blockIdx.x * (256 * S1_ITERS);
    for (int it = 0; it < S1_ITERS; ++it) {
        int p = base + it * 256 + threadIdx.x;
        unsigned pk = cwp[p];
        unsigned cw0 = pk & 0xFFFFu;
        unsigned cw1 = pk >> 16;
        int z = p % D;
        int r = p / D;
        int y = r % D;
        int x = r / D;
        int wx = min(x + 15, D - 1) - max(x - 16, 0) + 1;
        int wy = min(y + 15, D - 1) - max(y - 16, 0) + 1;
        int wz = min(z + 15, D - 1) - max(z - 16, 0) + 1;
        unsigned cw2 = (unsigned)(wx * wy * wz) - cw0 - cw1;
        float v0 = (cw0 > 100u) ? 1.f : 0.f;
        float v1 = (cw1 > 100u) ? 1.f : 0.f;
        float v2 = (cw2 > 100u) ? 1.f : 0.f;
        float border = (x >= HALF && x < D - HALF &&
                        y >= HALF && y < D - HALF &&
                        z >= HALF && z < D - HALF) ? 1.f : 0.f;
        float c = (border * v1 + v0 + v2 >= 2.f) ? 1.f : 0.f;
        cand[p] = c;
        float mean = (cw1 > 0u) ? cs[p] / fmaxf((float)cw1, 1.f) : 0.f;
        int idx = (int)rintf(c * mean);      // round half-to-even == jnp.round
        idx = min(max(idx, 0), NBINS - 1);
        idxbuf[p] = (unsigned short)idx;
        if (idx != 0) atomicAdd(&lh[idx], 1);  // hist[0] never consumed
    }
    __syncthreads();
    int* po = partial + blockIdx.x * NBINS;
    for (int i = threadIdx.x; i < NBINS; i += 256) po[i] = lh[i];
}

// stage 2: hist[bin] = sum over 500 block partials (coalesced, L2-resident)
__global__ __launch_bounds__(256) void hist_reduce_kernel(
    const int* __restrict__ partial, int* __restrict__ hist)
{
    int bin = blockIdx.x * 256 + threadIdx.x;   // 16 x 256 = 4096
    int s = 0;
    #pragma unroll 4
    for (int b = 0; b < S1_BLOCKS; ++b) s += partial[b * NBINS + bin];
    hist[bin] = s;
}

// ---------------------------------------------------------------------------
// histogram post-processing: rec -> ph_full (normalized), S = sum hist*ph
// ---------------------------------------------------------------------------
__global__ __launch_bounds__(256) void hist_post_kernel(
    const int* __restrict__ hist, float* __restrict__ ph_full,
    float* __restrict__ Sout)
{
    __shared__ float red[256];
    int t = threadIdx.x;

    float loc = 0.f;
    for (int b = t; b < NBINS; b += 256)
        if (b >= 1) loc += (float)hist[b];
    red[t] = loc; __syncthreads();
    for (int o = 128; o > 0; o >>= 1) { if (t < o) red[t] += red[t + o]; __syncthreads(); }
    float numb = red[0]; __syncthreads();

    loc = 0.f;
    for (int b = t; b < NBINS; b += 256) {
        float r = 0.f;
        if (b >= 1) {
            int h = hist[b];
            if (h > 0) r = numb / (float)h;
        }
        ph_full[b] = r;
        loc += r;
    }
    red[t] = loc; __syncthreads();
    for (int o = 128; o > 0; o >>= 1) { if (t < o) red[t] += red[t + o]; __syncthreads(); }
    float sumrec = red[0]; __syncthreads();

    loc = 0.f;
    for (int b = t; b < NBINS; b += 256) {
        float ph = (b >= 1) ? ph_full[b] / sumrec : 0.f;
        ph_full[b] = ph;
        loc += ph * (float)hist[b];
    }
    red[t] = loc; __syncthreads();
    for (int o = 128; o > 0; o >>= 1) { if (t < o) red[t] += red[t + o]; __syncthreads(); }
    if (t == 0) Sout[0] = red[0];
}

__global__ __launch_bounds__(256) void proba_kernel(
    const unsigned short* __restrict__ idxbuf,
    const float* __restrict__ ph_full, const float* __restrict__ Sv,
    float* __restrict__ outp)
{
    int p = blockIdx.x * blockDim.x + threadIdx.x;   // exact grid
    outp[p] = ph_full[idxbuf[p]] / Sv[0];
}

// ---------------------------------------------------------------------------
extern "C" void kernel_launch(void* const* d_in, const int* in_sizes, int n_in,
                              void* d_out, int out_size, void* d_ws, size_t ws_size,
                              hipStream_t stream)
{
    const float* data = (const float*)d_in[0];
    float* out   = (float*)d_out;
    float* cand  = out;
    float* proba = out + NVOX;

    char* ws = (char*)d_ws;
    const size_t NB = (size_t)NVOX * sizeof(float);
    float* W1 = (float*)(ws);
    float* W2 = (float*)(ws + NB);
    float* W3 = (float*)(ws + 2 * NB);
    int*   cnt  = (int*)(ws + 3 * NB);                 // NVOX+1 ints
    float* ph   = (float*)(ws + 4 * NB + 16);
    int*   hist = (int*)  (ws + 4 * NB + 16 + NBINS * 4);
    float* Sv   = (float*)(ws + 4 * NB + 16 + 2 * NBINS * 4);
    unsigned short* idxbuf = (unsigned short*)cnt;     // cnt dead after cs pass 1
    int* partial = (int*)W2;                           // W2 dead after cs pass 3

    dim3 eb(256), eg(NVOX / 256);          // 16000 blocks (scalar elementwise)
    dim3 rb(256), rg(DD / 32);             // 800 blocks (rotate box passes)
    dim3 sb(256), sg(2000);                // fused sweep tiles: 5*20*20

    hipMemsetAsync(cnt, 0, (NVOX + 1) * sizeof(int), stream);

    // cw packed box sums via rotate pipeline (pass 1 fuses pack + lab init)
    box_rot_int_kernel<0><<<rg, rb, 0, stream>>>(data, (unsigned*)W1, (int*)W2);
    box_rot_int_kernel<1><<<rg, rb, 0, stream>>>(W1, (unsigned*)W3, nullptr);
    box_rot_int_kernel<1><<<rg, rb, 0, stream>>>(W3, (unsigned*)W1, nullptr);
    unsigned* cwp = (unsigned*)W1;         // original layout
    int* lab = (int*)W2;

    // CCL: 16 synchronous sweeps as 8 fused-2 launches, ping-pong W2 <-> W3
    for (int s = 0; s < 8; ++s) {
        const int* src = (s & 1) ? (int*)W3 : (int*)W2;
        int*       dst = (s & 1) ? (int*)W2 : (int*)W3;
        ccl_sweep2_kernel<<<sg, sb, 0, stream>>>(src, dst);
    }
    lab = (int*)W2;                        // 8 launches -> result back in W2

    ccl_count_kernel<<<eg, eb, 0, stream>>>(lab, cnt);

    // cs float box sums via rotate pipeline (pass 1 fuses lsize*valid)
    box_rot_f32_kernel<0><<<rg, rb, 0, stream>>>(nullptr, lab, cnt, cwp, W3);
    box_rot_f32_kernel<1><<<rg, rb, 0, stream>>>(W3, nullptr, nullptr, nullptr, W2);
    box_rot_f32_kernel<1><<<rg, rb, 0, stream>>>(W2, nullptr, nullptr, nullptr, W3);
    float* cs = W3;                        // original layout

    // candidates + idx + two-stage histogram, then proba
    finalize_kernel<<<dim3(S1_BLOCKS), dim3(256), 0, stream>>>(cwp, cs, cand, idxbuf, partial);
    hist_reduce_kernel<<<dim3(16), dim3(256), 0, stream>>>(partial, hist);
    hist_post_kernel<<<1, 256, 0, stream>>>(hist, ph, Sv);
    proba_kernel<<<eg, eb, 0, stream>>>(idxbuf, ph, Sv, proba);
}

// Round 6
// 492.588 us; speedup vs baseline: 3.7220x; 1.2100x over previous
//
#include <hip/hip_runtime.h>
#include <cmath>

#define D 160
#define DD (D*D)          // 25600
#define NVOX (D*D*D)
#define BIGV (NVOX + 2)
#define NBINS 4096
#define HALF 16
#define RGRID 800         // rotate-pass blocks = DD/32, also hist partial count

// ---------------------------------------------------------------------------
// Rotate-pipeline box filter (window 32, 'same'), INT packed path.
// Buffer layout (a,b,c) c-contiguous; filter along c; write out[c*DD+a*D+b]
// -> layout (c,a,b). Three passes: (x,y,z)->(z,x,y)->(y,z,x)->(x,y,z).
// MODE 0 fuses class-pack from raw data + CCL lab init (original layout).
// cw0 low 16 bits, cw1 high 16 (max 32768, no carry). Int sums order-free.
// ---------------------------------------------------------------------------
template<int MODE>
__global__ __launch_bounds__(256) void box_rot_int_kernel(
    const void* __restrict__ vin, unsigned* __restrict__ out,
    int* __restrict__ lab)
{
    __shared__ unsigned tin[32][161];
    __shared__ unsigned filt[160][33];
    int L0 = blockIdx.x * 32;
    size_t base = (size_t)L0 * D;

    if (MODE == 0) {
        const float4* s4 = (const float4*)((const float*)vin + base);
        int4* lab4 = (int4*)(lab + base);
        for (int i = threadIdx.x; i < 32 * (D / 4); i += 256) {
            float4 v = s4[i];
            int e = i * 4, r = e / D, c = e - r * D;
            int p = (int)base + e;
            int4 lb; float rr;
            rr = rintf(v.x); tin[r][c]   = (rr==0.f) | ((rr==1.f)?0x10000u:0u); lb.x = (rr==1.f)?(p+1):BIGV;
            rr = rintf(v.y); tin[r][c+1] = (rr==0.f) | ((rr==1.f)?0x10000u:0u); lb.y = (rr==1.f)?(p+2):BIGV;
            rr = rintf(v.z); tin[r][c+2] = (rr==0.f) | ((rr==1.f)?0x10000u:0u); lb.z = (rr==1.f)?(p+3):BIGV;
            rr = rintf(v.w); tin[r][c+3] = (rr==0.f) | ((rr==1.f)?0x10000u:0u); lb.w = (rr==1.f)?(p+4):BIGV;
            lab4[i] = lb;
        }
    } else {
        const uint4* s4 = (const uint4*)((const unsigned*)vin + base);
        for (int i = threadIdx.x; i < 32 * (D / 4); i += 256) {
            uint4 v = s4[i];
            int e = i * 4, r = e / D, c = e - r * D;
            tin[r][c] = v.x; tin[r][c+1] = v.y; tin[r][c+2] = v.z; tin[r][c+3] = v.w;
        }
    }
    __syncthreads();

    {
        int r = threadIdx.x & 31, s = threadIdx.x >> 5;
        int i0 = 20 * s;
        const unsigned* ln = tin[r];
        unsigned sum = 0u;
        int jlo = i0 - 16; if (jlo < 0) jlo = 0;
        int jhi = i0 + 15; if (jhi > D - 1) jhi = D - 1;
        for (int j = jlo; j <= jhi; ++j) sum += ln[j];
        #pragma unroll 4
        for (int k = 0; k < 20; ++k) {
            int i = i0 + k;
            filt[i][r] = sum;
            int add = i + 16, rem = i - 16;
            if (add <= D - 1) sum += ln[add];
            if (rem >= 0)     sum -= ln[rem];
        }
    }
    __syncthreads();

    int r = threadIdx.x & 31;
    for (int c = (threadIdx.x >> 5); c < D; c += 8)
        out[(size_t)c * DD + L0 + r] = filt[c][r];
}

// ---------------------------------------------------------------------------
// Rotate box filter, FLOAT path. MODE 0 fuses the lsize*valid gather
// (lab,cnt,cwp in original layout). fp order differs from reference cumsum:
// perturbs only the proba path (~1e-7 vs 2e-2 threshold); candidates are
// integer-exact.
// ---------------------------------------------------------------------------
__global__ __launch_bounds__(256) void box_rot_f32_g_kernel(
    const int* __restrict__ lab, const int* __restrict__ cnt,
    const unsigned* __restrict__ cwp, float* __restrict__ out)
{
    __shared__ float tin[32][161];
    __shared__ float filt[160][33];
    int L0 = blockIdx.x * 32;
    size_t base = (size_t)L0 * D;

    const int4*  lab4 = (const int4*)(lab + base);
    const uint4* cw4  = (const uint4*)(cwp + base);
    for (int i = threadIdx.x; i < 32 * (D / 4); i += 256) {
        int4 l = lab4[i];
        uint4 cw = cw4[i];
        int e = i * 4, r = e / D, c = e - r * D;
        tin[r][c]   = (l.x != BIGV && (cw.x >> 16) > 100u) ? (float)cnt[l.x] : 0.f;
        tin[r][c+1] = (l.y != BIGV && (cw.y >> 16) > 100u) ? (float)cnt[l.y] : 0.f;
        tin[r][c+2] = (l.z != BIGV && (cw.z >> 16) > 100u) ? (float)cnt[l.z] : 0.f;
        tin[r][c+3] = (l.w != BIGV && (cw.w >> 16) > 100u) ? (float)cnt[l.w] : 0.f;
    }
    __syncthreads();

    {
        int r = threadIdx.x & 31, s = threadIdx.x >> 5;
        int i0 = 20 * s;
        const float* ln = tin[r];
        float sum = 0.f;
        int jlo = i0 - 16; if (jlo < 0) jlo = 0;
        int jhi = i0 + 15; if (jhi > D - 1) jhi = D - 1;
        for (int j = jlo; j <= jhi; ++j) sum += ln[j];
        #pragma unroll 4
        for (int k = 0; k < 20; ++k) {
            int i = i0 + k;
            filt[i][r] = sum;
            int add = i + 16, rem = i - 16;
            if (add <= D - 1) sum += ln[add];
            if (rem >= 0)     sum -= ln[rem];
        }
    }
    __syncthreads();

    int r = threadIdx.x & 31;
    for (int c = (threadIdx.x >> 5); c < D; c += 8)
        out[(size_t)c * DD + L0 + r] = filt[c][r];
}

// plain float middle pass
__global__ __launch_bounds__(256) void box_rot_f32_kernel(
    const float* __restrict__ fin, float* __restrict__ out)
{
    __shared__ float tin[32][161];
    __shared__ float filt[160][33];
    int L0 = blockIdx.x * 32;
    size_t base = (size_t)L0 * D;

    const float4* s4 = (const float4*)(fin + base);
    for (int i = threadIdx.x; i < 32 * (D / 4); i += 256) {
        float4 v = s4[i];
        int e = i * 4, r = e / D, c = e - r * D;
        tin[r][c] = v.x; tin[r][c+1] = v.y; tin[r][c+2] = v.z; tin[r][c+3] = v.w;
    }
    __syncthreads();

    {
        int r = threadIdx.x & 31, s = threadIdx.x >> 5;
        int i0 = 20 * s;
        const float* ln = tin[r];
        float sum = 0.f;
        int jlo = i0 - 16; if (jlo < 0) jlo = 0;
        int jhi = i0 + 15; if (jhi > D - 1) jhi = D - 1;
        for (int j = jlo; j <= jhi; ++j) sum += ln[j];
        #pragma unroll 4
        for (int k = 0; k < 20; ++k) {
            int i = i0 + k;
            filt[i][r] = sum;
            int add = i + 16, rem = i - 16;
            if (add <= D - 1) sum += ln[add];
            if (rem >= 0)     sum -= ln[rem];
        }
    }
    __syncthreads();

    int r = threadIdx.x & 31;
    for (int c = (threadIdx.x >> 5); c < D; c += 8)
        out[(size_t)c * DD + L0 + r] = filt[c][r];
}

// ---------------------------------------------------------------------------
// cs pass 3 fused with finalize: filter along x, and instead of storing cs,
// immediately compute candidates / bin idx / LDS histogram.
// Input layout (y,z,x): line L = y*D+z, elems along x. Output p = x*DD+L.
// ---------------------------------------------------------------------------
__global__ __launch_bounds__(256) void box_rot_fin_kernel(
    const float* __restrict__ fin, const unsigned* __restrict__ cwp,
    float* __restrict__ cand, unsigned short* __restrict__ idxbuf,
    int* __restrict__ partial)
{
    __shared__ float tin[32][161];
    __shared__ float filt[160][33];
    __shared__ int lh[NBINS];
    for (int i = threadIdx.x; i < NBINS; i += 256) lh[i] = 0;

    int L0 = blockIdx.x * 32;
    size_t base = (size_t)L0 * D;
    const float4* s4 = (const float4*)(fin + base);
    for (int i = threadIdx.x; i < 32 * (D / 4); i += 256) {
        float4 v = s4[i];
        int e = i * 4, r = e / D, c = e - r * D;
        tin[r][c] = v.x; tin[r][c+1] = v.y; tin[r][c+2] = v.z; tin[r][c+3] = v.w;
    }
    __syncthreads();

    {
        int r = threadIdx.x & 31, s = threadIdx.x >> 5;
        int i0 = 20 * s;
        const float* ln = tin[r];
        float sum = 0.f;
        int jlo = i0 - 16; if (jlo < 0) jlo = 0;
        int jhi = i0 + 15; if (jhi > D - 1) jhi = D - 1;
        for (int j = jlo; j <= jhi; ++j) sum += ln[j];
        #pragma unroll 4
        for (int k = 0; k < 20; ++k) {
            int i = i0 + k;
            filt[i][r] = sum;
            int add = i + 16, rem = i - 16;
            if (add <= D - 1) sum += ln[add];
            if (rem >= 0)     sum -= ln[rem];
        }
    }
    __syncthreads();

    int r = threadIdx.x & 31;
    int L = L0 + r;
    int y = L / D, z = L - (L / D) * D;
    bool byz = (y >= HALF && y < D - HALF && z >= HALF && z < D - HALF);
    int wy = min(y + 15, D - 1) - max(y - 16, 0) + 1;
    int wz = min(z + 15, D - 1) - max(z - 16, 0) + 1;
    for (int c = (threadIdx.x >> 5); c < D; c += 8) {   // c == x
        int p = c * DD + L;
        unsigned pk = cwp[p];
        unsigned cw0 = pk & 0xFFFFu;
        unsigned cw1 = pk >> 16;
        int wx = min(c + 15, D - 1) - max(c - 16, 0) + 1;
        unsigned cw2 = (unsigned)(wx * wy * wz) - cw0 - cw1;
        float v0 = (cw0 > 100u) ? 1.f : 0.f;
        float v1 = (cw1 > 100u) ? 1.f : 0.f;
        float v2 = (cw2 > 100u) ? 1.f : 0.f;
        float border = (byz && c >= HALF && c < D - HALF) ? 1.f : 0.f;
        float cd = (border * v1 + v0 + v2 >= 2.f) ? 1.f : 0.f;
        cand[p] = cd;
        float mean = (cw1 > 0u) ? filt[c][r] / fmaxf((float)cw1, 1.f) : 0.f;
        int idx = (int)rintf(cd * mean);    // round half-to-even == jnp.round
        idx = min(max(idx, 0), NBINS - 1);
        idxbuf[p] = (unsigned short)idx;
        if (idx != 0) atomicAdd(&lh[idx], 1);   // hist[0] never consumed
    }
    __syncthreads();
    int* po = partial + blockIdx.x * NBINS;
    for (int i = threadIdx.x; i < NBINS; i += 256) po[i] = lh[i];
}

// ---------------------------------------------------------------------------
// Flat CCL sweep, 8 consecutive z per thread (two int4 quads). z-neighbors
// via wave shuffle of already-held registers (8 | 160 -> a thread never
// straddles a line). 6-neighbor synchronous min, background stays BIGV.
// ---------------------------------------------------------------------------
__device__ __forceinline__ int min6(int c, int a, int b, int d, int e, int f, int g) {
    if (c == BIGV) return BIGV;
    return min(min(min(c, a), min(b, d)), min(min(e, f), g));
}

__device__ __forceinline__ void wave_count(int l, int lane, int* __restrict__ cnt) {
    unsigned long long remaining = __ballot(l != BIGV);
    while (remaining) {
        int leader = __ffsll((unsigned long long)remaining) - 1;
        int ll = __shfl(l, leader, 64);
        unsigned long long mm = __ballot(l == ll);
        if (lane == leader) atomicAdd(&cnt[ll], (int)__popcll(mm & remaining));
        remaining &= ~mm;
    }
}

template<int COUNT>
__global__ __launch_bounds__(256) void ccl_sweep8_kernel(
    const int* __restrict__ lab, int* __restrict__ outp,
    int* __restrict__ cnt)
{
    int t = blockIdx.x * 256 + threadIdx.x;   // exact grid NVOX/8
    int p = t * 8;
    int q = t * 2;
    const int4* lab4 = (const int4*)lab;
    int4 c0 = lab4[q], c1 = lab4[q + 1];

    int z0 = p % D;                            // multiple of 8
    int lane = threadIdx.x & 63;
    int lm = __shfl_up(c1.w, 1);               // lab[p-1]
    int rm = __shfl_down(c0.x, 1);             // lab[p+8]
    if (z0 == 0)          lm = BIGV;
    else if (lane == 0)   lm = lab[p - 1];
    if (z0 == D - 8)      rm = BIGV;
    else if (lane == 63)  rm = lab[p + 8];

    int r = p / D;
    int y = r % D;
    int x = r / D;
    const int4 BIG4 = make_int4(BIGV, BIGV, BIGV, BIGV);
    int4 yl0 = BIG4, yl1 = BIG4, yh0 = BIG4, yh1 = BIG4;
    int4 xl0 = BIG4, xl1 = BIG4, xh0 = BIG4, xh1 = BIG4;
    if (y > 0)     { yl0 = lab4[q - D/4];     yl1 = lab4[q - D/4 + 1]; }
    if (y < D - 1) { yh0 = lab4[q + D/4];     yh1 = lab4[q + D/4 + 1]; }
    if (x > 0)     { xl0 = lab4[q - DD/4];    xl1 = lab4[q - DD/4 + 1]; }
    if (x < D - 1) { xh0 = lab4[q + DD/4];    xh1 = lab4[q + DD/4 + 1]; }

    int4 o0, o1;
    o0.x = min6(c0.x, lm,   c0.y, yl0.x, yh0.x, xl0.x, xh0.x);
    o0.y = min6(c0.y, c0.x, c0.z, yl0.y, yh0.y, xl0.y, xh0.y);
    o0.z = min6(c0.z, c0.y, c0.w, yl0.z, yh0.z, xl0.z, xh0.z);
    o0.w = min6(c0.w, c0.z, c1.x, yl0.w, yh0.w, xl0.w, xh0.w);
    o1.x = min6(c1.x, c0.w, c1.y, yl1.x, yh1.x, xl1.x, xh1.x);
    o1.y = min6(c1.y, c1.x, c1.z, yl1.y, yh1.y, xl1.y, xh1.y);
    o1.z = min6(c1.z, c1.y, c1.w, yl1.z, yh1.z, xl1.z, xh1.z);
    o1.w = min6(c1.w, c1.z, rm,   yl1.w, yh1.w, xl1.w, xh1.w);

    int4* out4 = (int4*)outp;
    out4[q] = o0; out4[q + 1] = o1;

    if (COUNT) {   // final sweep: component-size count from registers
        wave_count(o0.x, lane, cnt);
        wave_count(o0.y, lane, cnt);
        wave_count(o0.z, lane, cnt);
        wave_count(o0.w, lane, cnt);
        wave_count(o1.x, lane, cnt);
        wave_count(o1.y, lane, cnt);
        wave_count(o1.z, lane, cnt);
        wave_count(o1.w, lane, cnt);
    }
}

// ---------------------------------------------------------------------------
// hist[bin] = sum over RGRID block partials (coalesced, L2-resident)
// ---------------------------------------------------------------------------
__global__ __launch_bounds__(256) void hist_reduce_kernel(
    const int* __restrict__ partial, int* __restrict__ hist)
{
    int bin = blockIdx.x * 256 + threadIdx.x;   // 16 x 256 = 4096
    int s = 0;
    #pragma unroll 4
    for (int b = 0; b < RGRID; ++b) s += partial[b * NBINS + bin];
    hist[bin] = s;
}

// ---------------------------------------------------------------------------
// histogram post-processing: rec -> ph_full (normalized), S = sum hist*ph
// ---------------------------------------------------------------------------
__global__ __launch_bounds__(256) void hist_post_kernel(
    const int* __restrict__ hist, float* __restrict__ ph_full,
    float* __restrict__ Sout)
{
    __shared__ float red[256];
    int t = threadIdx.x;

    float loc = 0.f;
    for (int b = t; b < NBINS; b += 256)
        if (b >= 1) loc += (float)hist[b];
    red[t] = loc; __syncthreads();
    for (int o = 128; o > 0; o >>= 1) { if (t < o) red[t] += red[t + o]; __syncthreads(); }
    float numb = red[0]; __syncthreads();

    loc = 0.f;
    for (int b = t; b < NBINS; b += 256) {
        float r = 0.f;
        if (b >= 1) {
            int h = hist[b];
            if (h > 0) r = numb / (float)h;
        }
        ph_full[b] = r;
        loc += r;
    }
    red[t] = loc; __syncthreads();
    for (int o = 128; o > 0; o >>= 1) { if (t < o) red[t] += red[t + o]; __syncthreads(); }
    float sumrec = red[0]; __syncthreads();

    loc = 0.f;
    for (int b = t; b < NBINS; b += 256) {
        float ph = (b >= 1) ? ph_full[b] / sumrec : 0.f;
        ph_full[b] = ph;
        loc += ph * (float)hist[b];
    }
    red[t] = loc; __syncthreads();
    for (int o = 128; o > 0; o >>= 1) { if (t < o) red[t] += red[t + o]; __syncthreads(); }
    if (t == 0) Sout[0] = red[0];
}

__global__ __launch_bounds__(256) void proba_kernel(
    const unsigned short* __restrict__ idxbuf,
    const float* __restrict__ ph_full, const float* __restrict__ Sv,
    float* __restrict__ outp)
{
    int p = blockIdx.x * blockDim.x + threadIdx.x;   // exact grid
    outp[p] = ph_full[idxbuf[p]] / Sv[0];
}

// ---------------------------------------------------------------------------
extern "C" void kernel_launch(void* const* d_in, const int* in_sizes, int n_in,
                              void* d_out, int out_size, void* d_ws, size_t ws_size,
                              hipStream_t stream)
{
    const float* data = (const float*)d_in[0];
    float* out   = (float*)d_out;
    float* cand  = out;
    float* proba = out + NVOX;

    char* ws = (char*)d_ws;
    const size_t NB = (size_t)NVOX * sizeof(float);
    float* W1 = (float*)(ws);
    float* W2 = (float*)(ws + NB);
    float* W3 = (float*)(ws + 2 * NB);
    int*   cnt  = (int*)(ws + 3 * NB);                 // NVOX+1 ints
    float* ph   = (float*)(ws + 4 * NB + 16);
    int*   hist = (int*)  (ws + 4 * NB + 16 + NBINS * 4);
    float* Sv   = (float*)(ws + 4 * NB + 16 + 2 * NBINS * 4);
    unsigned short* idxbuf = (unsigned short*)cnt;     // cnt dead after cs pass 1
    int* partial = (int*)W3;                           // W3 dead after cs pass 2

    dim3 eb(256), eg(NVOX / 256);          // 16000 blocks (proba)
    dim3 rb(256), rg(RGRID);               // 800 blocks (rotate passes)
    dim3 wb(256), wg(NVOX / 8 / 256);      // 2000 blocks (flat sweeps)

    hipMemsetAsync(cnt, 0, (NVOX + 1) * sizeof(int), stream);

    // cw packed box sums via rotate pipeline (pass 1 fuses pack + lab init)
    box_rot_int_kernel<0><<<rg, rb, 0, stream>>>(data, (unsigned*)W1, (int*)W2);
    box_rot_int_kernel<1><<<rg, rb, 0, stream>>>(W1, (unsigned*)W3, nullptr);
    box_rot_int_kernel<1><<<rg, rb, 0, stream>>>(W3, (unsigned*)W1, nullptr);
    unsigned* cwp = (unsigned*)W1;         // original layout
    int* lab = (int*)W2;

    // CCL: 16 flat synchronous sweeps, ping-pong W2 <-> W3;
    // sweep 16 fuses the component-size count (labels already in registers)
    for (int s = 0; s < 15; ++s) {
        const int* src = (s & 1) ? (int*)W3 : (int*)W2;
        int*       dst = (s & 1) ? (int*)W2 : (int*)W3;
        ccl_sweep8_kernel<0><<<wg, wb, 0, stream>>>(src, dst, nullptr);
    }
    ccl_sweep8_kernel<1><<<wg, wb, 0, stream>>>((int*)W3, (int*)W2, cnt);
    lab = (int*)W2;

    // cs float box sums (pass 1 fuses lsize*valid gather; pass 3 fuses
    // finalize: cand + idx + histogram — cs never materialized)
    box_rot_f32_g_kernel<<<rg, rb, 0, stream>>>(lab, cnt, cwp, W3);
    box_rot_f32_kernel<<<rg, rb, 0, stream>>>(W3, W2);
    box_rot_fin_kernel<<<rg, rb, 0, stream>>>(W2, cwp, cand, idxbuf, partial);

    hist_reduce_kernel<<<dim3(16), dim3(256), 0, stream>>>(partial, hist);
    hist_post_kernel<<<1, 256, 0, stream>>>(hist, ph, Sv);
    proba_kernel<<<eg, eb, 0, stream>>>(idxbuf, ph, Sv, proba);
}